// Round 1
// baseline (661.372 us; speedup 1.0000x reference)
//
#include <hip/hip_runtime.h>
#include <hip/hip_bf16.h>

// Problem constants: B=8, L=1024, D=1024, H=16, HD=64
#define B_ 8
#define L_ 1024
#define D_ 1024
#define H_ 16
#define HD_ 64

typedef short short8 __attribute__((ext_vector_type(8)));
typedef float floatx4 __attribute__((ext_vector_type(4)));
typedef unsigned short u16;

__device__ __forceinline__ u16 f2bf(float f) {
  union { float f; unsigned u; } v; v.f = f;
  unsigned r = v.u + 0x7fffu + ((v.u >> 16) & 1u);  // RNE
  return (u16)(r >> 16);
}

__device__ __forceinline__ floatx4 mfma16(short8 a, short8 b, floatx4 c) {
  return __builtin_amdgcn_mfma_f32_16x16x32_bf16(a, b, c, 0, 0, 0);
}

// C[M=8192,N=1024] = A[M,K=1024] @ Bw[K,N] + bias
// ABF16: A already bf16 (row-major) else fp32 (converted during staging)
// OUTHEAD: write bf16 into [B,H,L,HD] head layout; else fp32 row-major [M,N]
template<bool ABF16, bool OUTHEAD>
__global__ __launch_bounds__(256) void gemm_k(const void* __restrict__ Ap,
    const float* __restrict__ Bw, const float* __restrict__ bias,
    void* __restrict__ Cp)
{
  const int nt = blockIdx.x;          // N/128 = 8
  const int mt = blockIdx.y;          // M/128 = 64
  const int tid = threadIdx.x;
  const int lane = tid & 63, w = tid >> 6;
  const int quad = lane >> 4, l16 = lane & 15;
  const int wm = w >> 1, wn = w & 1;  // 2x2 wave grid, 64x64 per wave
  const int m0 = mt * 128, n0 = nt * 128;

  // stride 40 (pad 32->40): row byte stride 80, b128 reads land 2 lanes/bank (free)
  __shared__ __align__(16) u16 As[128 * 40];
  __shared__ __align__(16) u16 Bs[128 * 40];   // B^T tile: Bs[n][k]

  const floatx4 fzero = {0.f, 0.f, 0.f, 0.f};
  floatx4 acc[4][4];
  #pragma unroll
  for (int i = 0; i < 4; ++i)
    #pragma unroll
    for (int j = 0; j < 4; ++j) acc[i][j] = fzero;

  for (int k0 = 0; k0 < D_; k0 += 32) {
    // ---- stage A tile 128x32 ----
    if constexpr (ABF16) {
      const u16* A = (const u16*)Ap;
      #pragma unroll
      for (int i = 0; i < 2; ++i) {
        int c = i * 256 + tid;            // 512 chunks of 8 bf16
        int row = c >> 2, c8 = c & 3;
        short8 v = *(const short8*)(A + (size_t)(m0 + row) * D_ + k0 + c8 * 8);
        *(short8*)(&As[row * 40 + c8 * 8]) = v;
      }
    } else {
      const float* A = (const float*)Ap;
      #pragma unroll
      for (int i = 0; i < 4; ++i) {
        int c = i * 256 + tid;            // 1024 float4 chunks
        int row = c >> 3, c4 = c & 7;
        float4 v = *(const float4*)(A + (size_t)(m0 + row) * D_ + k0 + c4 * 4);
        ushort4 u;
        u.x = f2bf(v.x); u.y = f2bf(v.y); u.z = f2bf(v.z); u.w = f2bf(v.w);
        *(ushort4*)(&As[row * 40 + c4 * 4]) = u;
      }
    }
    // ---- stage B tile 32x128, transposed into Bs[n][k] ----
    #pragma unroll
    for (int i = 0; i < 4; ++i) {
      int c = i * 256 + tid;              // 1024 float4 chunks
      int row = c >> 5, c4 = c & 31;      // row = k-local, c4*4 = n-local
      float4 v = *(const float4*)(Bw + (size_t)(k0 + row) * D_ + n0 + c4 * 4);
      Bs[(c4 * 4 + 0) * 40 + row] = f2bf(v.x);
      Bs[(c4 * 4 + 1) * 40 + row] = f2bf(v.y);
      Bs[(c4 * 4 + 2) * 40 + row] = f2bf(v.z);
      Bs[(c4 * 4 + 3) * 40 + row] = f2bf(v.w);
    }
    __syncthreads();
    // ---- MFMA: 4x4 fragments of 16x16, K=32 in one mfma ----
    short8 af[4], bfr[4];
    #pragma unroll
    for (int mf = 0; mf < 4; ++mf)
      af[mf] = *(const short8*)(&As[(wm * 64 + mf * 16 + l16) * 40 + quad * 8]);
    #pragma unroll
    for (int nf = 0; nf < 4; ++nf)
      bfr[nf] = *(const short8*)(&Bs[(wn * 64 + nf * 16 + l16) * 40 + quad * 8]);
    #pragma unroll
    for (int mf = 0; mf < 4; ++mf)
      #pragma unroll
      for (int nf = 0; nf < 4; ++nf)
        acc[mf][nf] = mfma16(af[mf], bfr[nf], acc[mf][nf]);
    __syncthreads();
  }

  float bv[4];
  #pragma unroll
  for (int nf = 0; nf < 4; ++nf) bv[nf] = bias[n0 + wn * 64 + nf * 16 + l16];

  #pragma unroll
  for (int mf = 0; mf < 4; ++mf) {
    #pragma unroll
    for (int nf = 0; nf < 4; ++nf) {
      int n = n0 + wn * 64 + nf * 16 + l16;
      #pragma unroll
      for (int r = 0; r < 4; ++r) {
        int m = m0 + wm * 64 + mf * 16 + quad * 4 + r;  // C/D: col=l16, row=quad*4+r
        float val = acc[mf][nf][r] + bv[nf];
        if constexpr (OUTHEAD) {
          u16* C = (u16*)Cp;
          int b = m >> 10, l = m & 1023, hh = n >> 6, hd = n & 63;
          C[((size_t)((b * H_ + hh) * L_) + l) * HD_ + hd] = f2bf(val);
        } else {
          float* C = (float*)Cp;
          C[(size_t)m * D_ + n] = val;
        }
      }
    }
  }
}

// inv[b,h,k] = 1 / sum_q exp(S[q,k]/32); S = Qh @ Kh^T recomputed via MFMA.
__global__ __launch_bounds__(256) void colsum_k(const u16* __restrict__ Q,
    const u16* __restrict__ K, float* __restrict__ inv)
{
  const int kt = blockIdx.x, h = blockIdx.y, b = blockIdx.z;  // kt: 16 tiles of 64 cols
  const int tid = threadIdx.x;
  const int lane = tid & 63, w = tid >> 6;
  const int quad = lane >> 4, l16 = lane & 15;
  const size_t hb = (size_t)(b * H_ + h) * L_ * HD_;
  const u16* Qh = Q + hb;
  const u16* Kh = K + hb;
  const floatx4 fzero = {0.f, 0.f, 0.f, 0.f};

  // K fragments for this block's 64 columns (fixed over q sweep)
  short8 kf[4][2];
  #pragma unroll
  for (int nf = 0; nf < 4; ++nf)
    #pragma unroll
    for (int ks = 0; ks < 2; ++ks) {
      int col = kt * 64 + nf * 16 + l16;
      kf[nf][ks] = *(const short8*)(Kh + (size_t)col * HD_ + ks * 32 + quad * 8);
    }

  float cs[4] = {0.f, 0.f, 0.f, 0.f};
  for (int qc = 0; qc < 8; ++qc) {      // 8 chunks of 128 q rows
    short8 qf[2][2];
    #pragma unroll
    for (int mf = 0; mf < 2; ++mf)
      #pragma unroll
      for (int ks = 0; ks < 2; ++ks) {
        int m = qc * 128 + w * 32 + mf * 16 + l16;
        qf[mf][ks] = *(const short8*)(Qh + (size_t)m * HD_ + ks * 32 + quad * 8);
      }
    floatx4 sacc[2][4];
    #pragma unroll
    for (int mf = 0; mf < 2; ++mf)
      #pragma unroll
      for (int nf = 0; nf < 4; ++nf) sacc[mf][nf] = fzero;
    #pragma unroll
    for (int mf = 0; mf < 2; ++mf)
      #pragma unroll
      for (int nf = 0; nf < 4; ++nf)
        #pragma unroll
        for (int ks = 0; ks < 2; ++ks)
          sacc[mf][nf] = mfma16(qf[mf][ks], kf[nf][ks], sacc[mf][nf]);
    #pragma unroll
    for (int mf = 0; mf < 2; ++mf)
      #pragma unroll
      for (int nf = 0; nf < 4; ++nf)
        #pragma unroll
        for (int r = 0; r < 4; ++r)
          cs[nf] += __expf(sacc[mf][nf][r] * 0.03125f);
  }
  // reduce over quads (different q rows), then over waves
  #pragma unroll
  for (int nf = 0; nf < 4; ++nf) {
    cs[nf] += __shfl_xor(cs[nf], 16);
    cs[nf] += __shfl_xor(cs[nf], 32);
  }
  __shared__ float red[4][64];
  if (lane < 16) {
    #pragma unroll
    for (int nf = 0; nf < 4; ++nf) red[w][nf * 16 + l16] = cs[nf];
  }
  __syncthreads();
  if (tid < 64) {
    float t = red[0][tid] + red[1][tid] + red[2][tid] + red[3][tid];
    inv[(size_t)(b * H_ + h) * L_ + kt * 64 + tid] = 1.0f / t;
  }
}

// O[b, q, h*64+d] (bf16) = sum_k exp(S[q,k]/32)*inv[k] * V[k,d]
__global__ __launch_bounds__(256) void attn_k(const u16* __restrict__ Q,
    const u16* __restrict__ K, const u16* __restrict__ V,
    const float* __restrict__ inv, u16* __restrict__ O)
{
  const int qt = blockIdx.x, h = blockIdx.y, b = blockIdx.z;  // qt: 8 tiles of 128 q
  const int tid = threadIdx.x;
  const int lane = tid & 63, w = tid >> 6;
  const int quad = lane >> 4, l16 = lane & 15;
  const size_t hb = (size_t)(b * H_ + h) * L_ * HD_;
  const u16* Qh = Q + hb;
  const u16* Kh = K + hb;
  const u16* Vh = V + hb;
  const float* invh = inv + (size_t)(b * H_ + h) * L_;
  const floatx4 fzero = {0.f, 0.f, 0.f, 0.f};

  __shared__ __align__(16) u16 Ps[128 * 72];  // P tile, A-operand layout, stride 72
  __shared__ __align__(16) u16 Vs[64 * 72];   // V^T tile: Vs[d][k]

  // Q fragments: wave w owns q rows [qt*128 + w*32, +32)
  short8 qf[2][2];
  #pragma unroll
  for (int mf = 0; mf < 2; ++mf)
    #pragma unroll
    for (int ks = 0; ks < 2; ++ks) {
      int m = qt * 128 + w * 32 + mf * 16 + l16;
      qf[mf][ks] = *(const short8*)(Qh + (size_t)m * HD_ + ks * 32 + quad * 8);
    }

  floatx4 oacc[2][4];
  #pragma unroll
  for (int mf = 0; mf < 2; ++mf)
    #pragma unroll
    for (int nf = 0; nf < 4; ++nf) oacc[mf][nf] = fzero;

  for (int kc = 0; kc < 16; ++kc) {     // 16 chunks of 64 keys
    const int kk0 = kc * 64;
    // S = Q @ K^T for this chunk
    short8 kf[4][2];
    #pragma unroll
    for (int nf = 0; nf < 4; ++nf)
      #pragma unroll
      for (int ks = 0; ks < 2; ++ks) {
        int col = kk0 + nf * 16 + l16;
        kf[nf][ks] = *(const short8*)(Kh + (size_t)col * HD_ + ks * 32 + quad * 8);
      }
    floatx4 sacc[2][4];
    #pragma unroll
    for (int mf = 0; mf < 2; ++mf)
      #pragma unroll
      for (int nf = 0; nf < 4; ++nf) sacc[mf][nf] = fzero;
    #pragma unroll
    for (int mf = 0; mf < 2; ++mf)
      #pragma unroll
      for (int nf = 0; nf < 4; ++nf)
        #pragma unroll
        for (int ks = 0; ks < 2; ++ks)
          sacc[mf][nf] = mfma16(qf[mf][ks], kf[nf][ks], sacc[mf][nf]);

    // stage V chunk transposed: Vs[d][k_local]
    #pragma unroll
    for (int i = 0; i < 2; ++i) {
      int c = i * 256 + tid;            // 512 chunks of 8
      int row = c >> 3, c8 = c & 7;     // row = k_local, c8*8 = d base
      short8 v = *(const short8*)(Vh + (size_t)(kk0 + row) * HD_ + c8 * 8);
      #pragma unroll
      for (int j = 0; j < 8; ++j)
        Vs[(c8 * 8 + j) * 72 + row] = ((const u16*)&v)[j];
    }

    // P = exp(S/32)*inv -> LDS in A-operand-friendly layout
    float invv[4];
    #pragma unroll
    for (int nf = 0; nf < 4; ++nf) invv[nf] = invh[kk0 + nf * 16 + l16];
    #pragma unroll
    for (int mf = 0; mf < 2; ++mf)
      #pragma unroll
      for (int nf = 0; nf < 4; ++nf)
        #pragma unroll
        for (int r = 0; r < 4; ++r) {
          float p = __expf(sacc[mf][nf][r] * 0.03125f) * invv[nf];
          int ql = w * 32 + mf * 16 + quad * 4 + r;
          Ps[ql * 72 + nf * 16 + l16] = f2bf(p);
        }
    __syncthreads();

    // O += P @ V
    short8 pf[2][2], vf[4][2];
    #pragma unroll
    for (int mf = 0; mf < 2; ++mf)
      #pragma unroll
      for (int ks = 0; ks < 2; ++ks)
        pf[mf][ks] = *(const short8*)(&Ps[(w * 32 + mf * 16 + l16) * 72 + ks * 32 + quad * 8]);
    #pragma unroll
    for (int nf = 0; nf < 4; ++nf)
      #pragma unroll
      for (int ks = 0; ks < 2; ++ks)
        vf[nf][ks] = *(const short8*)(&Vs[(nf * 16 + l16) * 72 + ks * 32 + quad * 8]);
    #pragma unroll
    for (int mf = 0; mf < 2; ++mf)
      #pragma unroll
      for (int nf = 0; nf < 4; ++nf)
        #pragma unroll
        for (int ks = 0; ks < 2; ++ks)
          oacc[mf][nf] = mfma16(pf[mf][ks], vf[nf][ks], oacc[mf][nf]);
    __syncthreads();
  }

  // write attnout bf16 [B, L, D]
  #pragma unroll
  for (int mf = 0; mf < 2; ++mf)
    #pragma unroll
    for (int nf = 0; nf < 4; ++nf)
      #pragma unroll
      for (int r = 0; r < 4; ++r) {
        int q = qt * 128 + w * 32 + mf * 16 + quad * 4 + r;
        int d = nf * 16 + l16;
        O[((size_t)(b * L_ + q)) * D_ + h * HD_ + d] = f2bf(oacc[mf][nf][r]);
      }
}

extern "C" void kernel_launch(void* const* d_in, const int* in_sizes, int n_in,
                              void* d_out, int out_size, void* d_ws, size_t ws_size,
                              hipStream_t stream) {
  const float* xq = (const float*)d_in[0];
  const float* xk = (const float*)d_in[1];
  const float* xv = (const float*)d_in[2];
  // d_in[3] = mask: unused by reference
  const float* Wq = (const float*)d_in[4];
  const float* bq = (const float*)d_in[5];
  const float* Wk = (const float*)d_in[6];
  const float* bk = (const float*)d_in[7];
  const float* Wv = (const float*)d_in[8];
  const float* bv = (const float*)d_in[9];
  const float* Wo = (const float*)d_in[10];
  const float* bo = (const float*)d_in[11];

  // workspace layout (64.5 MB total):
  //   [0,16M)   Q bf16 [B,H,L,HD]
  //   [16,32M)  K bf16 [B,H,L,HD]
  //   [32,48M)  V bf16 [B,H,L,HD]
  //   [48,64M)  attnout bf16 [B,L,D]
  //   [64M,+512K) inv colsum fp32 [B,H,L]
  char* ws = (char*)d_ws;
  u16* Qb = (u16*)(ws);
  u16* Kb = (u16*)(ws + (16u << 20));
  u16* Vb = (u16*)(ws + (32u << 20));
  u16* Ob = (u16*)(ws + (48u << 20));
  float* invb = (float*)(ws + (64u << 20));

  dim3 blk(256);
  gemm_k<false, true><<<dim3(8, 64), blk, 0, stream>>>(xq, Wq, bq, Qb);
  gemm_k<false, true><<<dim3(8, 64), blk, 0, stream>>>(xk, Wk, bk, Kb);
  gemm_k<false, true><<<dim3(8, 64), blk, 0, stream>>>(xv, Wv, bv, Vb);
  colsum_k<<<dim3(16, 16, 8), blk, 0, stream>>>(Qb, Kb, invb);
  attn_k<<<dim3(8, 16, 8), blk, 0, stream>>>(Qb, Kb, Vb, invb, Ob);
  gemm_k<true, false><<<dim3(8, 64), blk, 0, stream>>>(Ob, Wo, bo, (float*)d_out);
}

// Round 2
// 443.742 us; speedup vs baseline: 1.4904x; 1.4904x over previous
//
#include <hip/hip_runtime.h>
#include <hip/hip_bf16.h>

// B=8, L=1024, D=1024, H=16, HD=64
#define B_ 8
#define L_ 1024
#define D_ 1024
#define H_ 16
#define HD_ 64

typedef short short8 __attribute__((ext_vector_type(8)));
typedef float floatx4 __attribute__((ext_vector_type(4)));
typedef unsigned short u16;

__device__ __forceinline__ u16 f2bf(float f) {          // RNE
  union { float f; unsigned u; } v; v.f = f;
  unsigned r = v.u + 0x7fffu + ((v.u >> 16) & 1u);
  return (u16)(r >> 16);
}
// pack bf16(a) low16, bf16(b) high16 (round-nearest-ties-up; ok for inner data)
__device__ __forceinline__ unsigned pk2(float a, float b) {
  union { float f; unsigned u; } x, y; x.f = a; y.f = b;
  return __builtin_amdgcn_perm(y.u + 0x8000u, x.u + 0x8000u, 0x07060302u);
}
__device__ __forceinline__ floatx4 mfma16(short8 a, short8 b, floatx4 c) {
  return __builtin_amdgcn_mfma_f32_16x16x32_bf16(a, b, c, 0, 0, 0);
}
__device__ __forceinline__ void gl2lds16(const void* g, void* l) {
  __builtin_amdgcn_global_load_lds(
      (const __attribute__((address_space(1))) void*)g,
      (__attribute__((address_space(3))) void*)l, 16, 0, 0);
}

// ---- W [K=1024, N=1024] fp32 -> Wt [N][K] bf16 (transpose + convert) ----
__global__ __launch_bounds__(256) void cvtw_k(const float* __restrict__ W,
                                              u16* __restrict__ Wt) {
  const int kt = blockIdx.x, nt = blockIdx.y;
  __shared__ __align__(16) u16 t[64 * 72];
  const int tid = threadIdx.x;
  #pragma unroll
  for (int i = 0; i < 4; ++i) {
    int idx = i * 256 + tid;
    int r = idx >> 4, c4 = idx & 15;
    float4 v = *(const float4*)(W + (size_t)(kt * 64 + r) * 1024 + nt * 64 + c4 * 4);
    t[(c4 * 4 + 0) * 72 + r] = f2bf(v.x);
    t[(c4 * 4 + 1) * 72 + r] = f2bf(v.y);
    t[(c4 * 4 + 2) * 72 + r] = f2bf(v.z);
    t[(c4 * 4 + 3) * 72 + r] = f2bf(v.w);
  }
  __syncthreads();
  #pragma unroll
  for (int i = 0; i < 2; ++i) {
    int idx = i * 256 + tid;
    int n = idx >> 3, k8 = idx & 7;
    short8 v = *(const short8*)(&t[n * 72 + k8 * 8]);
    *(short8*)(Wt + (size_t)(nt * 64 + n) * 1024 + kt * 64 + k8 * 8) = v;
  }
}

// ---- GEMM: C[M=8192,N=1024] = A[M,1024] @ Wt^T + bias ----
// AMODE: 0 = A fp32 (convert at frag read), 1 = A bf16
// OUTM : 0 = fp32 [M,N]; 1 = bf16 head [B,H,L,HD]; 2 = bf16 V^T [B*D][L] scaled by inv
template<int AMODE, int OUTM>
__global__ __launch_bounds__(256, 2) void gemm2_k(const void* __restrict__ Ap,
    const u16* __restrict__ Bt, const float* __restrict__ bias,
    void* __restrict__ Cp, const float* __restrict__ inv)
{
  const int nt = blockIdx.x, mt = blockIdx.y;
  const int tid = threadIdx.x, lane = tid & 63, w = tid >> 6;
  const int quad = lane >> 4, l16 = lane & 15;
  const int wm = w >> 1, wn = w & 1;
  const int m0 = mt * 128, n0 = nt * 128;

  constexpr int ABYTES = AMODE ? 8192 : 16384;
  constexpr int STG = ABYTES + 8192;
  constexpr int SBYTES = (OUTM == 2 && STG < 34816) ? 34816 : STG;
  __shared__ __align__(16) char smem[SBYTES];
  char* AsB = smem;
  char* BsB = smem + ABYTES;

  const floatx4 fz = {0.f, 0.f, 0.f, 0.f};
  floatx4 acc[4][4];
  #pragma unroll
  for (int i = 0; i < 4; ++i)
    #pragma unroll
    for (int j = 0; j < 4; ++j) acc[i][j] = fz;

  const int sw4 = (l16 & 3) ^ ((l16 >> 2) & 3);   // 4-slot xor swizzle (2-way banks)

  for (int k0 = 0; k0 < 1024; k0 += 32) {
    // stage Bt tile 128n x 32k bf16 (8KB) via global_load_lds, xor-swizzled slots
    #pragma unroll
    for (int seg = 0; seg < 2; ++seg) {
      int cI = seg * 256 + w * 64 + lane;
      int n = cI >> 2, sl = cI & 3;
      int kc = sl ^ ((n & 3) ^ ((n >> 2) & 3));
      gl2lds16(Bt + (size_t)(n0 + n) * 1024 + k0 + kc * 8, BsB + cI * 16);
    }
    if constexpr (AMODE == 0) {      // A fp32 tile 128x32 (16KB), 8 slots/row
      const float* A = (const float*)Ap;
      #pragma unroll
      for (int seg = 0; seg < 4; ++seg) {
        int cI = seg * 256 + w * 64 + lane;
        int r = cI >> 3, sl = cI & 7;
        int kc = sl ^ ((r & 7) ^ ((r >> 3) & 7));
        gl2lds16(A + (size_t)(m0 + r) * 1024 + k0 + kc * 4, AsB + cI * 16);
      }
    } else {                         // A bf16 tile 128x32 (8KB)
      const u16* A = (const u16*)Ap;
      #pragma unroll
      for (int seg = 0; seg < 2; ++seg) {
        int cI = seg * 256 + w * 64 + lane;
        int r = cI >> 2, sl = cI & 3;
        int kc = sl ^ ((r & 3) ^ ((r >> 2) & 3));
        gl2lds16(A + (size_t)(m0 + r) * 1024 + k0 + kc * 8, AsB + cI * 16);
      }
    }
    __syncthreads();

    short8 af[4], bfv[4];
    #pragma unroll
    for (int mf = 0; mf < 4; ++mf) {
      int row = wm * 64 + mf * 16 + l16;
      if constexpr (AMODE == 0) {
        int s0 = (quad * 2) ^ (l16 & 7) ^ ((mf * 2 + (l16 >> 3)) & 7);
        float4 x0 = *(const float4*)(AsB + row * 128 + s0 * 16);
        float4 x1 = *(const float4*)(AsB + row * 128 + (s0 ^ 1) * 16);
        union { uint4 u; short8 s; } uu;
        uu.u = make_uint4(pk2(x0.x, x0.y), pk2(x0.z, x0.w),
                          pk2(x1.x, x1.y), pk2(x1.z, x1.w));
        af[mf] = uu.s;
      } else {
        af[mf] = *(const short8*)(AsB + row * 64 + (quad ^ sw4) * 16);
      }
    }
    #pragma unroll
    for (int nf = 0; nf < 4; ++nf) {
      int row = wn * 64 + nf * 16 + l16;
      bfv[nf] = *(const short8*)(BsB + row * 64 + (quad ^ sw4) * 16);
    }
    #pragma unroll
    for (int mf = 0; mf < 4; ++mf)
      #pragma unroll
      for (int nf = 0; nf < 4; ++nf)
        acc[mf][nf] = mfma16(af[mf], bfv[nf], acc[mf][nf]);
    __syncthreads();
  }

  float bv[4];
  #pragma unroll
  for (int nf = 0; nf < 4; ++nf) bv[nf] = bias[n0 + wn * 64 + nf * 16 + l16];

  if constexpr (OUTM == 0) {
    float* C = (float*)Cp;
    #pragma unroll
    for (int mf = 0; mf < 4; ++mf)
      #pragma unroll
      for (int nf = 0; nf < 4; ++nf) {
        int n = n0 + wn * 64 + nf * 16 + l16;
        #pragma unroll
        for (int r = 0; r < 4; ++r) {
          int m = m0 + wm * 64 + mf * 16 + quad * 4 + r;
          C[(size_t)m * 1024 + n] = acc[mf][nf][r] + bv[nf];
        }
      }
  } else if constexpr (OUTM == 1) {
    u16* C = (u16*)Cp;
    #pragma unroll
    for (int mf = 0; mf < 4; ++mf)
      #pragma unroll
      for (int nf = 0; nf < 4; ++nf) {
        int n = n0 + wn * 64 + nf * 16 + l16;
        #pragma unroll
        for (int r = 0; r < 4; ++r) {
          int m = m0 + wm * 64 + mf * 16 + quad * 4 + r;
          int bb = m >> 10, l = m & 1023, hh = n >> 6, hd = n & 63;
          C[((size_t)((bb * H_ + hh) * L_) + l) * HD_ + hd] =
              f2bf(acc[mf][nf][r] + bv[nf]);
        }
      }
  } else {  // OUTM == 2: V^T epilogue, scaled by inv, via LDS transpose
    u16* ct = (u16*)smem;            // 128 x 136 u16 (34816 B)
    const int bb = m0 >> 10;
    const int hrow = bb * 16 + (n0 >> 6) + wn;
    float ivv[4][4];
    #pragma unroll
    for (int mf = 0; mf < 4; ++mf)
      #pragma unroll
      for (int r = 0; r < 4; ++r)
        ivv[mf][r] = inv[(size_t)hrow * 1024 + (m0 & 1023) + wm * 64 + mf * 16 + quad * 4 + r];
    #pragma unroll
    for (int mf = 0; mf < 4; ++mf)
      #pragma unroll
      for (int nf = 0; nf < 4; ++nf)
        #pragma unroll
        for (int r = 0; r < 4; ++r) {
          float val = (acc[mf][nf][r] + bv[nf]) * ivv[mf][r];
          ct[(wn * 64 + nf * 16 + l16) * 136 + wm * 64 + mf * 16 + quad * 4 + r] = f2bf(val);
        }
    __syncthreads();
    u16* Vt = (u16*)Cp;
    #pragma unroll
    for (int i = 0; i < 8; ++i) {
      int cc = i * 256 + tid;
      int n = cc >> 4, l8 = cc & 15;
      short8 v = *(const short8*)(&ct[n * 136 + l8 * 8]);
      *(short8*)(Vt + ((size_t)bb * 1024 + n0 + n) * 1024 + (m0 & 1023) + l8 * 8) = v;
    }
  }
}

// ---- inv[b,h,k] = 1 / sum_q exp(S[q,k]/32) (unchanged from r1, verified) ----
__global__ __launch_bounds__(256) void colsum_k(const u16* __restrict__ Q,
    const u16* __restrict__ K, float* __restrict__ inv)
{
  const int kt = blockIdx.x, h = blockIdx.y, b = blockIdx.z;
  const int tid = threadIdx.x;
  const int lane = tid & 63, w = tid >> 6;
  const int quad = lane >> 4, l16 = lane & 15;
  const size_t hb = (size_t)(b * H_ + h) * L_ * HD_;
  const u16* Qh = Q + hb;
  const u16* Kh = K + hb;
  const floatx4 fz = {0.f, 0.f, 0.f, 0.f};

  short8 kf[4][2];
  #pragma unroll
  for (int nf = 0; nf < 4; ++nf)
    #pragma unroll
    for (int ks = 0; ks < 2; ++ks) {
      int col = kt * 64 + nf * 16 + l16;
      kf[nf][ks] = *(const short8*)(Kh + (size_t)col * HD_ + ks * 32 + quad * 8);
    }

  float cs[4] = {0.f, 0.f, 0.f, 0.f};
  for (int qc = 0; qc < 8; ++qc) {
    short8 qf[2][2];
    #pragma unroll
    for (int mf = 0; mf < 2; ++mf)
      #pragma unroll
      for (int ks = 0; ks < 2; ++ks) {
        int m = qc * 128 + w * 32 + mf * 16 + l16;
        qf[mf][ks] = *(const short8*)(Qh + (size_t)m * HD_ + ks * 32 + quad * 8);
      }
    floatx4 sacc[2][4];
    #pragma unroll
    for (int mf = 0; mf < 2; ++mf)
      #pragma unroll
      for (int nf = 0; nf < 4; ++nf) sacc[mf][nf] = fz;
    #pragma unroll
    for (int mf = 0; mf < 2; ++mf)
      #pragma unroll
      for (int nf = 0; nf < 4; ++nf)
        #pragma unroll
        for (int ks = 0; ks < 2; ++ks)
          sacc[mf][nf] = mfma16(qf[mf][ks], kf[nf][ks], sacc[mf][nf]);
    #pragma unroll
    for (int mf = 0; mf < 2; ++mf)
      #pragma unroll
      for (int nf = 0; nf < 4; ++nf)
        #pragma unroll
        for (int r = 0; r < 4; ++r)
          cs[nf] += __expf(sacc[mf][nf][r] * 0.03125f);
  }
  #pragma unroll
  for (int nf = 0; nf < 4; ++nf) {
    cs[nf] += __shfl_xor(cs[nf], 16);
    cs[nf] += __shfl_xor(cs[nf], 32);
  }
  __shared__ float red[4][64];
  if (lane < 16) {
    #pragma unroll
    for (int nf = 0; nf < 4; ++nf) red[w][nf * 16 + l16] = cs[nf];
  }
  __syncthreads();
  if (tid < 64) {
    float t = red[0][tid] + red[1][tid] + red[2][tid] + red[3][tid];
    inv[(size_t)(b * H_ + h) * L_ + kt * 64 + tid] = 1.0f / t;
  }
}

// ---- attention: O[b,q,h*64+d] = sum_k exp(S/32) * Vt_scaled[d][k] ----
// S^T trick: C/D of S^T (col=q=l16, row=key=quad*4+r) IS the B-operand
// fragment of the PV K=32 mfma when two 16-key subtiles fill the 8 slots.
__global__ __launch_bounds__(256, 2) void attn2_k(const u16* __restrict__ Q,
    const u16* __restrict__ K, const u16* __restrict__ Vt, u16* __restrict__ O)
{
  const int qb = blockIdx.x, h = blockIdx.y, b = blockIdx.z;
  const int tid = threadIdx.x, lane = tid & 63, w = tid >> 6;
  const int quad = lane >> 4, l16 = lane & 15;
  const size_t hb = (size_t)(b * H_ + h) * L_ * HD_;
  const u16* Qh = Q + hb;
  const u16* Kh = K + hb;
  const u16* Vh = Vt + ((size_t)b * D_ + h * HD_) * L_;   // rows d, stride L
  const int q0 = qb * 256 + w * 64;
  const floatx4 fz = {0.f, 0.f, 0.f, 0.f};
  const float cexp = 0.04508422f;   // log2(e)/32

  short8 qf[4][2];                  // B-operand frags of Q (n=q=l16, k=hd)
  #pragma unroll
  for (int qs = 0; qs < 4; ++qs)
    #pragma unroll
    for (int ks = 0; ks < 2; ++ks)
      qf[qs][ks] = *(const short8*)(Qh + (size_t)(q0 + qs * 16 + l16) * HD_ + ks * 32 + quad * 8);

  floatx4 oT[4][4];                 // O^T tiles: row d=ds*16+quad*4+r, col q=qs*16+l16
  #pragma unroll
  for (int i = 0; i < 4; ++i)
    #pragma unroll
    for (int j = 0; j < 4; ++j) oT[i][j] = fz;

  for (int kk = 0; kk < L_; kk += 32) {
    short8 ka[2][2];                // A-operand frags of K (m=key=l16)
    #pragma unroll
    for (int kt = 0; kt < 2; ++kt)
      #pragma unroll
      for (int ks = 0; ks < 2; ++ks)
        ka[kt][ks] = *(const short8*)(Kh + (size_t)(kk + kt * 16 + l16) * HD_ + ks * 32 + quad * 8);

    floatx4 st[2][4];               // S^T: col=q, row=key
    #pragma unroll
    for (int kt = 0; kt < 2; ++kt)
      #pragma unroll
      for (int qs = 0; qs < 4; ++qs) {
        floatx4 s = mfma16(ka[kt][0], qf[qs][0], fz);
        st[kt][qs] = mfma16(ka[kt][1], qf[qs][1], s);
      }

    short8 va[4];                   // A frags of V^T: m=d=l16; k slots: 4 keys kk+quad*4.., 4 keys kk+16+quad*4..
    #pragma unroll
    for (int ds = 0; ds < 4; ++ds) {
      const u16* vp = Vh + (size_t)(ds * 16 + l16) * L_ + kk + quad * 4;
      uint2 lo = *(const uint2*)(vp);
      uint2 hi = *(const uint2*)(vp + 16);
      union { uint4 u; short8 s; } uv;
      uv.u = make_uint4(lo.x, lo.y, hi.x, hi.y);
      va[ds] = uv.s;
    }

    short8 pt[4];                   // P^T as B-operand frags (from S^T C/D, in-lane)
    #pragma unroll
    for (int qs = 0; qs < 4; ++qs) {
      float e0 = __builtin_amdgcn_exp2f(st[0][qs][0] * cexp);
      float e1 = __builtin_amdgcn_exp2f(st[0][qs][1] * cexp);
      float e2 = __builtin_amdgcn_exp2f(st[0][qs][2] * cexp);
      float e3 = __builtin_amdgcn_exp2f(st[0][qs][3] * cexp);
      float f0 = __builtin_amdgcn_exp2f(st[1][qs][0] * cexp);
      float f1 = __builtin_amdgcn_exp2f(st[1][qs][1] * cexp);
      float f2 = __builtin_amdgcn_exp2f(st[1][qs][2] * cexp);
      float f3 = __builtin_amdgcn_exp2f(st[1][qs][3] * cexp);
      union { uint4 u; short8 s; } pu;
      pu.u = make_uint4(pk2(e0, e1), pk2(e2, e3), pk2(f0, f1), pk2(f2, f3));
      pt[qs] = pu.s;
    }
    #pragma unroll
    for (int ds = 0; ds < 4; ++ds)
      #pragma unroll
      for (int qs = 0; qs < 4; ++qs)
        oT[ds][qs] = mfma16(va[ds], pt[qs], oT[ds][qs]);
  }

  // transpose O^T -> O via per-wave LDS region, then coalesced b128 stores
  __shared__ __align__(16) u16 ot[4][64 * 72];
  #pragma unroll
  for (int ds = 0; ds < 4; ++ds)
    #pragma unroll
    for (int qs = 0; qs < 4; ++qs)
      #pragma unroll
      for (int r = 0; r < 4; ++r)
        ot[w][(qs * 16 + l16) * 72 + ds * 16 + quad * 4 + r] = f2bf(oT[ds][qs][r]);
  __syncthreads();
  #pragma unroll
  for (int i = 0; i < 8; ++i) {
    int cc = i * 64 + lane;
    int ql = cc >> 3, d8 = cc & 7;
    short8 v = *(const short8*)(&ot[w][ql * 72 + d8 * 8]);
    *(short8*)(O + ((size_t)b * L_ + q0 + ql) * D_ + h * HD_ + d8 * 8) = v;
  }
}

extern "C" void kernel_launch(void* const* d_in, const int* in_sizes, int n_in,
                              void* d_out, int out_size, void* d_ws, size_t ws_size,
                              hipStream_t stream) {
  const float* xq = (const float*)d_in[0];
  const float* xk = (const float*)d_in[1];
  const float* xv = (const float*)d_in[2];
  const float* Wq = (const float*)d_in[4];
  const float* bq = (const float*)d_in[5];
  const float* Wk = (const float*)d_in[6];
  const float* bk = (const float*)d_in[7];
  const float* Wv = (const float*)d_in[8];
  const float* bv = (const float*)d_in[9];
  const float* Wo = (const float*)d_in[10];
  const float* bo = (const float*)d_in[11];

  // ws: 4 x 16MiB pools (64 MiB total, known-safe)
  //  P0: Vt bf16 [B*D][L]      (later: WT2 for Wo)
  //  P1: Q bf16 [B,H,L,HD]
  //  P2: K bf16 [B,H,L,HD]
  //  P3: WT bf16 2MiB + inv fp32 0.5MiB @ +2MiB  (later: attnout Ob bf16)
  char* ws = (char*)d_ws;
  const size_t MB16 = 16u << 20;
  u16* Vtb  = (u16*)(ws);
  u16* Qb   = (u16*)(ws + MB16);
  u16* Kb   = (u16*)(ws + 2 * MB16);
  u16* WT   = (u16*)(ws + 3 * MB16);
  float* invb = (float*)(ws + 3 * MB16 + (2u << 20));
  u16* Ob   = (u16*)(ws + 3 * MB16);
  u16* WT2  = (u16*)(ws);

  dim3 blk(256);
  dim3 gw(16, 16);
  dim3 gg(8, 64);

  cvtw_k<<<gw, blk, 0, stream>>>(Wq, WT);
  gemm2_k<0, 1><<<gg, blk, 0, stream>>>(xq, WT, bq, Qb, nullptr);
  cvtw_k<<<gw, blk, 0, stream>>>(Wk, WT);
  gemm2_k<0, 1><<<gg, blk, 0, stream>>>(xk, WT, bk, Kb, nullptr);
  colsum_k<<<dim3(16, 16, 8), blk, 0, stream>>>(Qb, Kb, invb);
  cvtw_k<<<gw, blk, 0, stream>>>(Wv, WT);
  gemm2_k<0, 2><<<gg, blk, 0, stream>>>(xv, WT, bv, Vtb, invb);
  attn2_k<<<dim3(4, 16, 8), blk, 0, stream>>>(Qb, Kb, Vtb, Ob);
  cvtw_k<<<gw, blk, 0, stream>>>(Wo, WT2);
  gemm2_k<1, 0><<<gg, blk, 0, stream>>>(Ob, WT2, bo, (float*)d_out, nullptr);
}

// Round 3
// 373.418 us; speedup vs baseline: 1.7711x; 1.1883x over previous
//
#include <hip/hip_runtime.h>
#include <hip/hip_bf16.h>

// B=8, L=1024, D=1024, H=16, HD=64
#define B_ 8
#define L_ 1024
#define D_ 1024
#define H_ 16
#define HD_ 64

typedef short short8 __attribute__((ext_vector_type(8)));
typedef float floatx4 __attribute__((ext_vector_type(4)));
typedef unsigned short u16;

__device__ __forceinline__ u16 f2bf(float f) {          // RNE
  union { float f; unsigned u; } v; v.f = f;
  unsigned r = v.u + 0x7fffu + ((v.u >> 16) & 1u);
  return (u16)(r >> 16);
}
// pack bf16(a) low16, bf16(b) high16
__device__ __forceinline__ unsigned pk2(float a, float b) {
  union { float f; unsigned u; } x, y; x.f = a; y.f = b;
  return __builtin_amdgcn_perm(y.u + 0x8000u, x.u + 0x8000u, 0x07060302u);
}
__device__ __forceinline__ floatx4 mfma16(short8 a, short8 b, floatx4 c) {
  return __builtin_amdgcn_mfma_f32_16x16x32_bf16(a, b, c, 0, 0, 0);
}
__device__ __forceinline__ void gl2lds16(const void* g, void* l) {
  __builtin_amdgcn_global_load_lds(
      (const __attribute__((address_space(1))) void*)g,
      (__attribute__((address_space(3))) void*)l, 16, 0, 0);
}

// ---- x fp32 [8M] -> bf16 [8M], 8 elems/thread ----
__global__ __launch_bounds__(256) void cvtx_k(const float* __restrict__ x,
                                              u16* __restrict__ y) {
  size_t i = ((size_t)blockIdx.x * 256 + threadIdx.x) * 8;
  float4 a = *(const float4*)(x + i);
  float4 b = *(const float4*)(x + i + 4);
  uint4 u = make_uint4(pk2(a.x, a.y), pk2(a.z, a.w), pk2(b.x, b.y), pk2(b.z, b.w));
  *(uint4*)(y + i) = u;
}

// ---- W [K=1024, N=1024] fp32 -> Wt [N][K] bf16 ----
__global__ __launch_bounds__(256) void cvtw_k(const float* __restrict__ W,
                                              u16* __restrict__ Wt) {
  const int kt = blockIdx.x, nt = blockIdx.y;
  __shared__ __align__(16) u16 t[64 * 72];
  const int tid = threadIdx.x;
  #pragma unroll
  for (int i = 0; i < 4; ++i) {
    int idx = i * 256 + tid;
    int r = idx >> 4, c4 = idx & 15;
    float4 v = *(const float4*)(W + (size_t)(kt * 64 + r) * 1024 + nt * 64 + c4 * 4);
    t[(c4 * 4 + 0) * 72 + r] = f2bf(v.x);
    t[(c4 * 4 + 1) * 72 + r] = f2bf(v.y);
    t[(c4 * 4 + 2) * 72 + r] = f2bf(v.z);
    t[(c4 * 4 + 3) * 72 + r] = f2bf(v.w);
  }
  __syncthreads();
  #pragma unroll
  for (int i = 0; i < 2; ++i) {
    int idx = i * 256 + tid;
    int n = idx >> 3, k8 = idx & 7;
    short8 v = *(const short8*)(&t[n * 72 + k8 * 8]);
    *(short8*)(Wt + (size_t)(nt * 64 + n) * 1024 + kt * 64 + k8 * 8) = v;
  }
}

// ---- GEMM: C[8192,1024] = A @ Wt^T + bias ----
// AMODE: 0 = A fp32, 1 = A bf16
// OUTM : 0 = fp32 [M,N]; 1 = bf16 head [B,H,L,HD];
//        2 = bf16 V^T [B*D][L] scaled by inv[key], keys PERMUTED within
//            32-groups: pos = g*32 + quad*8 + kt*4 + r  <- key g*32+kt*16+quad*4+r
template<int AMODE, int OUTM>
__global__ __launch_bounds__(256, 2) void gemm2_k(const void* __restrict__ Ap,
    const u16* __restrict__ Bt, const float* __restrict__ bias,
    void* __restrict__ Cp, const float* __restrict__ inv)
{
  const int nt = blockIdx.x, mt = blockIdx.y;
  const int tid = threadIdx.x, lane = tid & 63, w = tid >> 6;
  const int quad = lane >> 4, l16 = lane & 15;
  const int wm = w >> 1, wn = w & 1;
  const int m0 = mt * 128, n0 = nt * 128;

  constexpr int ABYTES = AMODE ? 8192 : 16384;
  constexpr int STG = ABYTES + 8192;
  constexpr int SBYTES = (OUTM == 2 && STG < 34816) ? 34816 : STG;
  __shared__ __align__(16) char smem[SBYTES];
  char* AsB = smem;
  char* BsB = smem + ABYTES;

  const floatx4 fz = {0.f, 0.f, 0.f, 0.f};
  floatx4 acc[4][4];
  #pragma unroll
  for (int i = 0; i < 4; ++i)
    #pragma unroll
    for (int j = 0; j < 4; ++j) acc[i][j] = fz;

  const int sw4 = (l16 & 3) ^ ((l16 >> 2) & 3);

  for (int k0 = 0; k0 < 1024; k0 += 32) {
    #pragma unroll
    for (int seg = 0; seg < 2; ++seg) {
      int cI = seg * 256 + w * 64 + lane;
      int n = cI >> 2, sl = cI & 3;
      int kc = sl ^ ((n & 3) ^ ((n >> 2) & 3));
      gl2lds16(Bt + (size_t)(n0 + n) * 1024 + k0 + kc * 8, BsB + cI * 16);
    }
    if constexpr (AMODE == 0) {
      const float* A = (const float*)Ap;
      #pragma unroll
      for (int seg = 0; seg < 4; ++seg) {
        int cI = seg * 256 + w * 64 + lane;
        int r = cI >> 3, sl = cI & 7;
        int kc = sl ^ ((r & 7) ^ ((r >> 3) & 7));
        gl2lds16(A + (size_t)(m0 + r) * 1024 + k0 + kc * 4, AsB + cI * 16);
      }
    } else {
      const u16* A = (const u16*)Ap;
      #pragma unroll
      for (int seg = 0; seg < 2; ++seg) {
        int cI = seg * 256 + w * 64 + lane;
        int r = cI >> 2, sl = cI & 3;
        int kc = sl ^ ((r & 3) ^ ((r >> 2) & 3));
        gl2lds16(A + (size_t)(m0 + r) * 1024 + k0 + kc * 8, AsB + cI * 16);
      }
    }
    __syncthreads();

    short8 af[4], bfv[4];
    #pragma unroll
    for (int mf = 0; mf < 4; ++mf) {
      int row = wm * 64 + mf * 16 + l16;
      if constexpr (AMODE == 0) {
        int s0 = (quad * 2) ^ (l16 & 7) ^ ((mf * 2 + (l16 >> 3)) & 7);
        float4 x0 = *(const float4*)(AsB + row * 128 + s0 * 16);
        float4 x1 = *(const float4*)(AsB + row * 128 + (s0 ^ 1) * 16);
        union { uint4 u; short8 s; } uu;
        uu.u = make_uint4(pk2(x0.x, x0.y), pk2(x0.z, x0.w),
                          pk2(x1.x, x1.y), pk2(x1.z, x1.w));
        af[mf] = uu.s;
      } else {
        af[mf] = *(const short8*)(AsB + row * 64 + (quad ^ sw4) * 16);
      }
    }
    #pragma unroll
    for (int nf = 0; nf < 4; ++nf) {
      int row = wn * 64 + nf * 16 + l16;
      bfv[nf] = *(const short8*)(BsB + row * 64 + (quad ^ sw4) * 16);
    }
    #pragma unroll
    for (int mf = 0; mf < 4; ++mf)
      #pragma unroll
      for (int nf = 0; nf < 4; ++nf)
        acc[mf][nf] = mfma16(af[mf], bfv[nf], acc[mf][nf]);
    __syncthreads();
  }

  float bv[4];
  #pragma unroll
  for (int nf = 0; nf < 4; ++nf) bv[nf] = bias[n0 + wn * 64 + nf * 16 + l16];

  if constexpr (OUTM == 0) {
    float* C = (float*)Cp;
    #pragma unroll
    for (int mf = 0; mf < 4; ++mf)
      #pragma unroll
      for (int nf = 0; nf < 4; ++nf) {
        int n = n0 + wn * 64 + nf * 16 + l16;
        #pragma unroll
        for (int r = 0; r < 4; ++r) {
          int m = m0 + wm * 64 + mf * 16 + quad * 4 + r;
          C[(size_t)m * 1024 + n] = acc[mf][nf][r] + bv[nf];
        }
      }
  } else if constexpr (OUTM == 1) {
    u16* C = (u16*)Cp;
    #pragma unroll
    for (int mf = 0; mf < 4; ++mf)
      #pragma unroll
      for (int nf = 0; nf < 4; ++nf) {
        int n = n0 + wn * 64 + nf * 16 + l16;
        #pragma unroll
        for (int r = 0; r < 4; ++r) {
          int m = m0 + wm * 64 + mf * 16 + quad * 4 + r;
          int bb = m >> 10, l = m & 1023, hh = n >> 6, hd = n & 63;
          C[((size_t)((bb * H_ + hh) * L_) + l) * HD_ + hd] =
              f2bf(acc[mf][nf][r] + bv[nf]);
        }
      }
  } else {  // OUTM == 2: scaled V^T, permuted key order
    u16* ct = (u16*)smem;            // 128 x 136 u16
    const int bb = m0 >> 10;
    const int hrow = bb * 16 + (n0 >> 6) + wn;
    float ivv[4][4];
    #pragma unroll
    for (int mf = 0; mf < 4; ++mf)
      #pragma unroll
      for (int r = 0; r < 4; ++r)
        ivv[mf][r] = inv[(size_t)hrow * 1024 + (m0 & 1023) + wm * 64 + mf * 16 + quad * 4 + r];
    #pragma unroll
    for (int mf = 0; mf < 4; ++mf)
      #pragma unroll
      for (int nf = 0; nf < 4; ++nf)
        #pragma unroll
        for (int r = 0; r < 4; ++r) {
          float val = (acc[mf][nf][r] + bv[nf]) * ivv[mf][r];
          ct[(wn * 64 + nf * 16 + l16) * 136 + wm * 64 + mf * 16 + quad * 4 + r] = f2bf(val);
        }
    __syncthreads();
    u16* Vt = (u16*)Cp;
    #pragma unroll
    for (int i = 0; i < 8; ++i) {
      int cc = i * 256 + tid;
      int n = cc >> 4, l8 = cc & 15;
      int g = l8 >> 2, q2 = l8 & 3;
      int mloc = g * 32 + q2 * 4;
      uint2 lo = *(const uint2*)(&ct[n * 136 + mloc]);
      uint2 hi = *(const uint2*)(&ct[n * 136 + mloc + 16]);
      uint4 uv = make_uint4(lo.x, lo.y, hi.x, hi.y);
      *(uint4*)(Vt + ((size_t)bb * 1024 + n0 + n) * 1024 + (m0 & 1023) + l8 * 8) = uv;
    }
  }
}

// ---- colsum: inv[b,h,k] = 1/sum_q exp(S[q,k]/32); Q staged in LDS ----
// grid (4,16,8); wave w owns keys ktb*256 + w*64 (disjoint -> no cross-wave reduce)
__global__ __launch_bounds__(256, 2) void colsum2_k(const u16* __restrict__ Q,
    const u16* __restrict__ K, float* __restrict__ inv)
{
  const int ktb = blockIdx.x, h = blockIdx.y, b = blockIdx.z;
  const int tid = threadIdx.x, lane = tid & 63, w = tid >> 6;
  const int quad = lane >> 4, l16 = lane & 15;
  const size_t hb = (size_t)(b * H_ + h) * L_ * HD_;
  const u16* Qh = Q + hb;
  const u16* Kh = K + hb;
  const int kbase = ktb * 256 + w * 64;
  const floatx4 fz = {0.f, 0.f, 0.f, 0.f};
  const float cexp = 0.04508422f;   // log2(e)/32

  __shared__ __align__(16) u16 qsm[8192];   // 128 q-rows x 64, swizzled 16B slots

  short8 kf[4][2];
  #pragma unroll
  for (int nf = 0; nf < 4; ++nf)
    #pragma unroll
    for (int ks = 0; ks < 2; ++ks)
      kf[nf][ks] = *(const short8*)(Kh + (size_t)(kbase + nf * 16 + l16) * 64 + ks * 32 + quad * 8);

  float cs[4] = {0.f, 0.f, 0.f, 0.f};
  for (int qc = 0; qc < 8; ++qc) {
    #pragma unroll
    for (int seg = 0; seg < 4; ++seg) {
      int cI = seg * 256 + w * 64 + lane;
      int row = cI >> 3, sl = cI & 7;
      gl2lds16(Qh + (size_t)(qc * 128 + row) * 64 + ((sl ^ (row & 7)) * 8), (char*)qsm + cI * 16);
    }
    __syncthreads();
    #pragma unroll
    for (int mf = 0; mf < 8; ++mf) {
      short8 qf0 = *(const short8*)(&qsm[(mf * 16 + l16) * 64 + ((quad ^ (l16 & 7)) * 8)]);
      short8 qf1 = *(const short8*)(&qsm[(mf * 16 + l16) * 64 + (((4 + quad) ^ (l16 & 7)) * 8)]);
      floatx4 sacc[4];
      #pragma unroll
      for (int nf = 0; nf < 4; ++nf) {
        floatx4 s = mfma16(qf0, kf[nf][0], fz);
        sacc[nf] = mfma16(qf1, kf[nf][1], s);
      }
      #pragma unroll
      for (int nf = 0; nf < 4; ++nf)
        #pragma unroll
        for (int r = 0; r < 4; ++r)
          cs[nf] += __builtin_amdgcn_exp2f(sacc[nf][r] * cexp);
    }
    __syncthreads();
  }
  #pragma unroll
  for (int nf = 0; nf < 4; ++nf) {
    cs[nf] += __shfl_xor(cs[nf], 16);
    cs[nf] += __shfl_xor(cs[nf], 32);
  }
  if (quad == 0) {
    #pragma unroll
    for (int nf = 0; nf < 4; ++nf)
      inv[(size_t)(b * H_ + h) * L_ + kbase + nf * 16 + l16] = 1.0f / cs[nf];
  }
}

// ---- attention: LDS-staged K and permuted V^T chunks (64 keys/iter) ----
__global__ __launch_bounds__(256, 2) void attn3_k(const u16* __restrict__ Q,
    const u16* __restrict__ K, const u16* __restrict__ Vt, u16* __restrict__ O)
{
  const int qb = blockIdx.x, h = blockIdx.y, b = blockIdx.z;
  const int tid = threadIdx.x, lane = tid & 63, w = tid >> 6;
  const int quad = lane >> 4, l16 = lane & 15;
  const size_t hb = (size_t)(b * H_ + h) * L_ * HD_;
  const u16* Qh = Q + hb;
  const u16* Kh = K + hb;
  const u16* Vh = Vt + ((size_t)b * D_ + h * HD_) * L_;   // [d][pos], stride L
  const int q0 = qb * 256 + w * 64;
  const floatx4 fz = {0.f, 0.f, 0.f, 0.f};
  const float cexp = 0.04508422f;   // log2(e)/32

  // union: staging K(8KB)+V(8KB) while looping; ot transpose (36864B) after
  __shared__ __align__(16) u16 smem[18432];
  u16* ksb = smem;            // [key 64][64] swizzled
  u16* vsb = smem + 4096;     // [d 64][64 pos] swizzled

  short8 qf[4][2];            // B-operand frags of Q
  #pragma unroll
  for (int qs = 0; qs < 4; ++qs)
    #pragma unroll
    for (int ks = 0; ks < 2; ++ks)
      qf[qs][ks] = *(const short8*)(Qh + (size_t)(q0 + qs * 16 + l16) * 64 + ks * 32 + quad * 8);

  floatx4 oT[4][4];           // O^T: row d=ds*16+quad*4+r, col q=qs*16+l16
  #pragma unroll
  for (int i = 0; i < 4; ++i)
    #pragma unroll
    for (int j = 0; j < 4; ++j) oT[i][j] = fz;

  for (int kc = 0; kc < 16; ++kc) {
    const int kk = kc * 64;
    #pragma unroll
    for (int seg = 0; seg < 2; ++seg) {       // K chunk: 64 rows x 128B
      int cI = seg * 256 + w * 64 + lane;
      int row = cI >> 3, sl = cI & 7;
      gl2lds16(Kh + (size_t)(kk + row) * 64 + ((sl ^ (row & 7)) * 8), (char*)ksb + cI * 16);
    }
    #pragma unroll
    for (int seg = 0; seg < 2; ++seg) {       // V chunk: 64 d-rows x 128B
      int cI = seg * 256 + w * 64 + lane;
      int row = cI >> 3, sl = cI & 7;
      gl2lds16(Vh + (size_t)row * L_ + kk + ((sl ^ (row & 7)) * 8), (char*)vsb + cI * 16);
    }
    __syncthreads();

    short8 pt[2][4];
    #pragma unroll
    for (int p = 0; p < 2; ++p) {
      short8 ka0[2], ka1[2];
      #pragma unroll
      for (int ks = 0; ks < 2; ++ks) {
        ka0[ks] = *(const short8*)(&ksb[((2 * p) * 16 + l16) * 64 + (((ks * 4 + quad) ^ (l16 & 7)) * 8)]);
        ka1[ks] = *(const short8*)(&ksb[((2 * p + 1) * 16 + l16) * 64 + (((ks * 4 + quad) ^ (l16 & 7)) * 8)]);
      }
      #pragma unroll
      for (int qs = 0; qs < 4; ++qs) {
        floatx4 s0 = mfma16(ka0[0], qf[qs][0], fz);
        s0 = mfma16(ka0[1], qf[qs][1], s0);
        floatx4 s1 = mfma16(ka1[0], qf[qs][0], fz);
        s1 = mfma16(ka1[1], qf[qs][1], s1);
        float e0 = __builtin_amdgcn_exp2f(s0[0] * cexp);
        float e1 = __builtin_amdgcn_exp2f(s0[1] * cexp);
        float e2 = __builtin_amdgcn_exp2f(s0[2] * cexp);
        float e3 = __builtin_amdgcn_exp2f(s0[3] * cexp);
        float f0 = __builtin_amdgcn_exp2f(s1[0] * cexp);
        float f1 = __builtin_amdgcn_exp2f(s1[1] * cexp);
        float f2 = __builtin_amdgcn_exp2f(s1[2] * cexp);
        float f3 = __builtin_amdgcn_exp2f(s1[3] * cexp);
        union { uint4 u; short8 s; } pu;
        pu.u = make_uint4(pk2(e0, e1), pk2(e2, e3), pk2(f0, f1), pk2(f2, f3));
        pt[p][qs] = pu.s;
      }
    }
    #pragma unroll
    for (int p = 0; p < 2; ++p) {
      #pragma unroll
      for (int ds = 0; ds < 4; ++ds) {
        short8 va = *(const short8*)(&vsb[(ds * 16 + l16) * 64 + (((p * 4 + quad) ^ (l16 & 7)) * 8)]);
        #pragma unroll
        for (int qs = 0; qs < 4; ++qs)
          oT[ds][qs] = mfma16(va, pt[p][qs], oT[ds][qs]);
      }
    }
    __syncthreads();
  }

  // transpose O^T -> O via per-wave LDS region (reuses staging memory)
  u16* ot = smem + w * 4608;   // 64 x 72
  #pragma unroll
  for (int ds = 0; ds < 4; ++ds)
    #pragma unroll
    for (int qs = 0; qs < 4; ++qs)
      #pragma unroll
      for (int r = 0; r < 4; ++r)
        ot[(qs * 16 + l16) * 72 + ds * 16 + quad * 4 + r] = f2bf(oT[ds][qs][r]);
  __syncthreads();
  #pragma unroll
  for (int i = 0; i < 8; ++i) {
    int cc = i * 64 + lane;
    int ql = cc >> 3, d8 = cc & 7;
    short8 v = *(const short8*)(&ot[ql * 72 + d8 * 8]);
    *(short8*)(O + ((size_t)b * L_ + q0 + ql) * D_ + h * HD_ + d8 * 8) = v;
  }
}

extern "C" void kernel_launch(void* const* d_in, const int* in_sizes, int n_in,
                              void* d_out, int out_size, void* d_ws, size_t ws_size,
                              hipStream_t stream) {
  const float* xq = (const float*)d_in[0];
  const float* xk = (const float*)d_in[1];
  const float* xv = (const float*)d_in[2];
  const float* Wq = (const float*)d_in[4];
  const float* bq = (const float*)d_in[5];
  const float* Wk = (const float*)d_in[6];
  const float* bk = (const float*)d_in[7];
  const float* Wv = (const float*)d_in[8];
  const float* bv = (const float*)d_in[9];
  const float* Wo = (const float*)d_in[10];
  const float* bo = (const float*)d_in[11];

  // 4 x 16MiB pools, 64 MiB high-water (r1-proven-safe footprint):
  //  P0: xq_bf -> xk_bf -> Vt
  //  P1: Q -> WT_o (after attn)
  //  P2: K
  //  P3: WT (2MB) + inv (0.5MB @ +2MB) -> Ob (full 16MB, after V gemm)
  char* ws = (char*)d_ws;
  const size_t MB16 = 16u << 20;
  u16* Xbf  = (u16*)(ws);
  u16* Vtb  = (u16*)(ws);
  u16* Qb   = (u16*)(ws + MB16);
  u16* WT2  = (u16*)(ws + MB16);
  u16* Kb   = (u16*)(ws + 2 * MB16);
  u16* WT   = (u16*)(ws + 3 * MB16);
  float* invb = (float*)(ws + 3 * MB16 + (2u << 20));
  u16* Ob   = (u16*)(ws + 3 * MB16);

  dim3 blk(256);
  dim3 gw(16, 16);
  dim3 gg(8, 64);

  cvtx_k<<<4096, blk, 0, stream>>>(xq, Xbf);
  cvtw_k<<<gw, blk, 0, stream>>>(Wq, WT);
  gemm2_k<1, 1><<<gg, blk, 0, stream>>>(Xbf, WT, bq, Qb, nullptr);

  cvtx_k<<<4096, blk, 0, stream>>>(xk, Xbf);
  cvtw_k<<<gw, blk, 0, stream>>>(Wk, WT);
  gemm2_k<1, 1><<<gg, blk, 0, stream>>>(Xbf, WT, bk, Kb, nullptr);

  colsum2_k<<<dim3(4, 16, 8), blk, 0, stream>>>(Qb, Kb, invb);

  cvtw_k<<<gw, blk, 0, stream>>>(Wv, WT);
  gemm2_k<0, 2><<<gg, blk, 0, stream>>>(xv, WT, bv, Vtb, invb);

  attn3_k<<<dim3(4, 16, 8), blk, 0, stream>>>(Qb, Kb, Vtb, Ob);

  cvtw_k<<<gw, blk, 0, stream>>>(Wo, WT2);
  gemm2_k<1, 0><<<gg, blk, 0, stream>>>(Ob, WT2, bo, (float*)d_out, nullptr);
}

// Round 4
// 335.902 us; speedup vs baseline: 1.9689x; 1.1117x over previous
//
#include <hip/hip_runtime.h>
#include <hip/hip_bf16.h>

// B=8, L=1024, D=1024, H=16, HD=64
#define B_ 8
#define L_ 1024
#define D_ 1024
#define H_ 16
#define HD_ 64

typedef short short8 __attribute__((ext_vector_type(8)));
typedef float floatx4 __attribute__((ext_vector_type(4)));
typedef unsigned short u16;

__device__ __forceinline__ u16 f2bf(float f) {          // RNE
  union { float f; unsigned u; } v; v.f = f;
  unsigned r = v.u + 0x7fffu + ((v.u >> 16) & 1u);
  return (u16)(r >> 16);
}
// pack bf16(a) low16, bf16(b) high16
__device__ __forceinline__ unsigned pk2(float a, float b) {
  union { float f; unsigned u; } x, y; x.f = a; y.f = b;
  return __builtin_amdgcn_perm(y.u + 0x8000u, x.u + 0x8000u, 0x07060302u);
}
__device__ __forceinline__ floatx4 mfma16(short8 a, short8 b, floatx4 c) {
  return __builtin_amdgcn_mfma_f32_16x16x32_bf16(a, b, c, 0, 0, 0);
}
__device__ __forceinline__ void gl2lds16(const void* g, void* l) {
  __builtin_amdgcn_global_load_lds(
      (const __attribute__((address_space(1))) void*)g,
      (__attribute__((address_space(3))) void*)l, 16, 0, 0);
}

// ---- 3x: x fp32 [8M] -> bf16, grid (4096, nsel) ----
__global__ __launch_bounds__(256) void cvtx3_k(const float* __restrict__ x0,
    const float* __restrict__ x1, const float* __restrict__ x2,
    u16* __restrict__ y0, u16* __restrict__ y1, u16* __restrict__ y2) {
  const float* x = blockIdx.y == 0 ? x0 : (blockIdx.y == 1 ? x1 : x2);
  u16* y = blockIdx.y == 0 ? y0 : (blockIdx.y == 1 ? y1 : y2);
  size_t i = ((size_t)blockIdx.x * 256 + threadIdx.x) * 8;
  float4 a = *(const float4*)(x + i);
  float4 b = *(const float4*)(x + i + 4);
  uint4 u = make_uint4(pk2(a.x, a.y), pk2(a.z, a.w), pk2(b.x, b.y), pk2(b.z, b.w));
  *(uint4*)(y + i) = u;
}

// ---- 4x: W [K,N] fp32 -> Wt [N][K] bf16, grid (16,16,4) ----
__global__ __launch_bounds__(256) void cvtw4_k(
    const float* __restrict__ W0, const float* __restrict__ W1,
    const float* __restrict__ W2, const float* __restrict__ W3,
    u16* __restrict__ T0, u16* __restrict__ T1,
    u16* __restrict__ T2, u16* __restrict__ T3) {
  const int z = blockIdx.z;
  const float* W = z == 0 ? W0 : (z == 1 ? W1 : (z == 2 ? W2 : W3));
  u16* Wt = z == 0 ? T0 : (z == 1 ? T1 : (z == 2 ? T2 : T3));
  const int kt = blockIdx.x, nt = blockIdx.y;
  __shared__ __align__(16) u16 t[64 * 72];
  const int tid = threadIdx.x;
  #pragma unroll
  for (int i = 0; i < 4; ++i) {
    int idx = i * 256 + tid;
    int r = idx >> 4, c4 = idx & 15;
    float4 v = *(const float4*)(W + (size_t)(kt * 64 + r) * 1024 + nt * 64 + c4 * 4);
    t[(c4 * 4 + 0) * 72 + r] = f2bf(v.x);
    t[(c4 * 4 + 1) * 72 + r] = f2bf(v.y);
    t[(c4 * 4 + 2) * 72 + r] = f2bf(v.z);
    t[(c4 * 4 + 3) * 72 + r] = f2bf(v.w);
  }
  __syncthreads();
  #pragma unroll
  for (int i = 0; i < 2; ++i) {
    int idx = i * 256 + tid;
    int n = idx >> 3, k8 = idx & 7;
    short8 v = *(const short8*)(&t[n * 72 + k8 * 8]);
    *(short8*)(Wt + (size_t)(nt * 64 + n) * 1024 + kt * 64 + k8 * 8) = v;
  }
}

// ---- GEMM: C[8192,1024] = A @ Wt^T + bias ----  BK=64
// AMODE: 0 = A fp32, 1 = A bf16
// OUTM : 0 = fp32 [M,N]; 1 = bf16 head [B,H,L,HD];
//        2 = bf16 V^T [B*D][L] scaled by inv[key], keys PERMUTED within
//            32-groups: pos = g*32 + quad*8 + kt*4 + r  <- key g*32+kt*16+quad*4+r
template<int AMODE, int OUTM>
__global__ __launch_bounds__(256, 2) void gemm2_k(const void* __restrict__ Ap,
    const u16* __restrict__ Bt, const float* __restrict__ bias,
    void* __restrict__ Cp, const float* __restrict__ inv)
{
  const int nt = blockIdx.x, mt = blockIdx.y;
  const int tid = threadIdx.x, lane = tid & 63, w = tid >> 6;
  const int quad = lane >> 4, l16 = lane & 15;
  const int wm = w >> 1, wn = w & 1;
  const int m0 = mt * 128, n0 = nt * 128;

  constexpr int ABYTES = AMODE ? 16384 : 32768;
  constexpr int STG = ABYTES + 16384;
  constexpr int SBYTES = (OUTM == 2 && STG < 34816) ? 34816 : STG;
  __shared__ __align__(16) char smem[SBYTES];
  char* AsB = smem;
  char* BsB = smem + ABYTES;

  const floatx4 fz = {0.f, 0.f, 0.f, 0.f};
  floatx4 acc[4][4];
  #pragma unroll
  for (int i = 0; i < 4; ++i)
    #pragma unroll
    for (int j = 0; j < 4; ++j) acc[i][j] = fz;

  for (int k0 = 0; k0 < 1024; k0 += 64) {
    // B tile: 128 rows x 64k bf16 (128B row, 8 slots, xor-swizzled)
    #pragma unroll
    for (int seg = 0; seg < 4; ++seg) {
      int cI = seg * 256 + w * 64 + lane;
      int r = cI >> 3, sl = cI & 7;
      int kc = sl ^ (r & 7);
      gl2lds16(Bt + (size_t)(n0 + r) * 1024 + k0 + kc * 8, BsB + cI * 16);
    }
    if constexpr (AMODE == 0) {   // A fp32: 128 rows x 256B, 16 slots
      const float* A = (const float*)Ap;
      #pragma unroll
      for (int seg = 0; seg < 8; ++seg) {
        int cI = seg * 256 + w * 64 + lane;
        int r = cI >> 4, sl = cI & 15;
        int kc = sl ^ (r & 15);
        gl2lds16(A + (size_t)(m0 + r) * 1024 + k0 + kc * 4, AsB + cI * 16);
      }
    } else {                      // A bf16: 128 rows x 128B, 8 slots
      const u16* A = (const u16*)Ap;
      #pragma unroll
      for (int seg = 0; seg < 4; ++seg) {
        int cI = seg * 256 + w * 64 + lane;
        int r = cI >> 3, sl = cI & 7;
        int kc = sl ^ (r & 7);
        gl2lds16(A + (size_t)(m0 + r) * 1024 + k0 + kc * 8, AsB + cI * 16);
      }
    }
    __syncthreads();

    #pragma unroll
    for (int ks = 0; ks < 2; ++ks) {
      short8 af[4], bfv[4];
      #pragma unroll
      for (int mf = 0; mf < 4; ++mf) {
        int row = wm * 64 + mf * 16 + l16;
        if constexpr (AMODE == 0) {
          int L0 = ks * 8 + quad * 2;
          float4 x0 = *(const float4*)(AsB + row * 256 + ((L0) ^ l16) * 16);
          float4 x1 = *(const float4*)(AsB + row * 256 + ((L0 + 1) ^ l16) * 16);
          union { uint4 u; short8 s; } uu;
          uu.u = make_uint4(pk2(x0.x, x0.y), pk2(x0.z, x0.w),
                            pk2(x1.x, x1.y), pk2(x1.z, x1.w));
          af[mf] = uu.s;
        } else {
          af[mf] = *(const short8*)(AsB + row * 128 + (((ks * 4 + quad) ^ (l16 & 7)) * 16));
        }
      }
      #pragma unroll
      for (int nf = 0; nf < 4; ++nf) {
        int row = wn * 64 + nf * 16 + l16;
        bfv[nf] = *(const short8*)(BsB + row * 128 + (((ks * 4 + quad) ^ (l16 & 7)) * 16));
      }
      #pragma unroll
      for (int mf = 0; mf < 4; ++mf)
        #pragma unroll
        for (int nf = 0; nf < 4; ++nf)
          acc[mf][nf] = mfma16(af[mf], bfv[nf], acc[mf][nf]);
    }
    __syncthreads();
  }

  float bv[4];
  #pragma unroll
  for (int nf = 0; nf < 4; ++nf) bv[nf] = bias[n0 + wn * 64 + nf * 16 + l16];

  if constexpr (OUTM == 0) {
    float* C = (float*)Cp;
    #pragma unroll
    for (int mf = 0; mf < 4; ++mf)
      #pragma unroll
      for (int nf = 0; nf < 4; ++nf) {
        int n = n0 + wn * 64 + nf * 16 + l16;
        #pragma unroll
        for (int r = 0; r < 4; ++r) {
          int m = m0 + wm * 64 + mf * 16 + quad * 4 + r;
          C[(size_t)m * 1024 + n] = acc[mf][nf][r] + bv[nf];
        }
      }
  } else if constexpr (OUTM == 1) {
    u16* C = (u16*)Cp;
    #pragma unroll
    for (int mf = 0; mf < 4; ++mf)
      #pragma unroll
      for (int nf = 0; nf < 4; ++nf) {
        int n = n0 + wn * 64 + nf * 16 + l16;
        #pragma unroll
        for (int r = 0; r < 4; ++r) {
          int m = m0 + wm * 64 + mf * 16 + quad * 4 + r;
          int bb = m >> 10, l = m & 1023, hh = n >> 6, hd = n & 63;
          C[((size_t)((bb * H_ + hh) * L_) + l) * HD_ + hd] =
              f2bf(acc[mf][nf][r] + bv[nf]);
        }
      }
  } else {  // OUTM == 2: scaled V^T, permuted key order
    u16* ct = (u16*)smem;            // 128 x 136 u16
    const int bb = m0 >> 10;
    const int hrow = bb * 16 + (n0 >> 6) + wn;
    float ivv[4][4];
    #pragma unroll
    for (int mf = 0; mf < 4; ++mf)
      #pragma unroll
      for (int r = 0; r < 4; ++r)
        ivv[mf][r] = inv[(size_t)hrow * 1024 + (m0 & 1023) + wm * 64 + mf * 16 + quad * 4 + r];
    __syncthreads();
    #pragma unroll
    for (int mf = 0; mf < 4; ++mf)
      #pragma unroll
      for (int nf = 0; nf < 4; ++nf)
        #pragma unroll
        for (int r = 0; r < 4; ++r) {
          float val = (acc[mf][nf][r] + bv[nf]) * ivv[mf][r];
          ct[(wn * 64 + nf * 16 + l16) * 136 + wm * 64 + mf * 16 + quad * 4 + r] = f2bf(val);
        }
    __syncthreads();
    u16* Vt = (u16*)Cp;
    #pragma unroll
    for (int i = 0; i < 8; ++i) {
      int cc = i * 256 + tid;
      int n = cc >> 4, l8 = cc & 15;
      int g = l8 >> 2, q2 = l8 & 3;
      int mloc = g * 32 + q2 * 4;
      uint2 lo = *(const uint2*)(&ct[n * 136 + mloc]);
      uint2 hi = *(const uint2*)(&ct[n * 136 + mloc + 16]);
      uint4 uv = make_uint4(lo.x, lo.y, hi.x, hi.y);
      *(uint4*)(Vt + ((size_t)bb * 1024 + n0 + n) * 1024 + (m0 & 1023) + l8 * 8) = uv;
    }
  }
}

// ---- colsum: inv[b,h,k] = 1/sum_q exp(S[q,k]/32); Q in LDS, 256-q chunks ----
// grid (4,16,8); wave w owns keys ktb*256 + w*64
__global__ __launch_bounds__(256, 2) void colsum2_k(const u16* __restrict__ Q,
    const u16* __restrict__ K, float* __restrict__ inv)
{
  const int ktb = blockIdx.x, h = blockIdx.y, b = blockIdx.z;
  const int tid = threadIdx.x, lane = tid & 63, w = tid >> 6;
  const int quad = lane >> 4, l16 = lane & 15;
  const size_t hb = (size_t)(b * H_ + h) * L_ * HD_;
  const u16* Qh = Q + hb;
  const u16* Kh = K + hb;
  const int kbase = ktb * 256 + w * 64;
  const floatx4 fz = {0.f, 0.f, 0.f, 0.f};
  const float cexp = 0.04508422f;   // log2(e)/32

  __shared__ __align__(16) u16 qsm[16384];   // 256 q-rows x 64 bf16, swizzled

  short8 kf[4][2];
  #pragma unroll
  for (int nf = 0; nf < 4; ++nf)
    #pragma unroll
    for (int ks = 0; ks < 2; ++ks)
      kf[nf][ks] = *(const short8*)(Kh + (size_t)(kbase + nf * 16 + l16) * 64 + ks * 32 + quad * 8);

  float cs[4] = {0.f, 0.f, 0.f, 0.f};
  for (int qc = 0; qc < 4; ++qc) {
    #pragma unroll
    for (int seg = 0; seg < 8; ++seg) {
      int cI = seg * 256 + w * 64 + lane;
      int row = cI >> 3, sl = cI & 7;
      gl2lds16(Qh + (size_t)(qc * 256 + row) * 64 + ((sl ^ (row & 7)) * 8), (char*)qsm + cI * 16);
    }
    __syncthreads();
    #pragma unroll
    for (int mf = 0; mf < 16; ++mf) {
      short8 qf0 = *(const short8*)(&qsm[(mf * 16 + l16) * 64 + ((quad ^ (l16 & 7)) * 8)]);
      short8 qf1 = *(const short8*)(&qsm[(mf * 16 + l16) * 64 + (((4 + quad) ^ (l16 & 7)) * 8)]);
      floatx4 sacc[4];
      #pragma unroll
      for (int nf = 0; nf < 4; ++nf) {
        floatx4 s = mfma16(qf0, kf[nf][0], fz);
        sacc[nf] = mfma16(qf1, kf[nf][1], s);
      }
      #pragma unroll
      for (int nf = 0; nf < 4; ++nf)
        #pragma unroll
        for (int r = 0; r < 4; ++r)
          cs[nf] += __builtin_amdgcn_exp2f(sacc[nf][r] * cexp);
    }
    __syncthreads();
  }
  #pragma unroll
  for (int nf = 0; nf < 4; ++nf) {
    cs[nf] += __shfl_xor(cs[nf], 16);
    cs[nf] += __shfl_xor(cs[nf], 32);
  }
  if (quad == 0) {
    #pragma unroll
    for (int nf = 0; nf < 4; ++nf)
      inv[(size_t)(b * H_ + h) * L_ + kbase + nf * 16 + l16] = 1.0f / cs[nf];
  }
}

// ---- attention: LDS-staged K + permuted V^T, 128-key chunks ----
__global__ __launch_bounds__(256, 2) void attn3_k(const u16* __restrict__ Q,
    const u16* __restrict__ K, const u16* __restrict__ Vt, u16* __restrict__ O)
{
  const int qb = blockIdx.x, h = blockIdx.y, b = blockIdx.z;
  const int tid = threadIdx.x, lane = tid & 63, w = tid >> 6;
  const int quad = lane >> 4, l16 = lane & 15;
  const size_t hb = (size_t)(b * H_ + h) * L_ * HD_;
  const u16* Qh = Q + hb;
  const u16* Kh = K + hb;
  const u16* Vh = Vt + ((size_t)b * D_ + h * HD_) * L_;   // [d][pos], stride L
  const int q0 = qb * 256 + w * 64;
  const floatx4 fz = {0.f, 0.f, 0.f, 0.f};
  const float cexp = 0.04508422f;   // log2(e)/32

  // staging: K 16KB (128 keys x 64, 8 slots) + V 16KB (64 d x 128 pos, 16 slots)
  // epilogue: ot transpose 36864B (4 waves x 64x72 u16)
  __shared__ __align__(16) u16 smem[18432];
  u16* ksb = smem;            // byte-addressed via (char*)
  u16* vsb = smem + 8192;

  short8 qf[4][2];            // B-operand frags of Q
  #pragma unroll
  for (int qs = 0; qs < 4; ++qs)
    #pragma unroll
    for (int ks = 0; ks < 2; ++ks)
      qf[qs][ks] = *(const short8*)(Qh + (size_t)(q0 + qs * 16 + l16) * 64 + ks * 32 + quad * 8);

  floatx4 oT[4][4];           // O^T: row d=ds*16+quad*4+r, col q=qs*16+l16
  #pragma unroll
  for (int i = 0; i < 4; ++i)
    #pragma unroll
    for (int j = 0; j < 4; ++j) oT[i][j] = fz;

  for (int kc = 0; kc < 8; ++kc) {
    const int kk = kc * 128;
    #pragma unroll
    for (int seg = 0; seg < 4; ++seg) {       // K: 128 rows x 128B
      int cI = seg * 256 + w * 64 + lane;
      int row = cI >> 3, sl = cI & 7;
      gl2lds16(Kh + (size_t)(kk + row) * 64 + ((sl ^ (row & 7)) * 8), (char*)ksb + cI * 16);
    }
    #pragma unroll
    for (int seg = 0; seg < 4; ++seg) {       // V: 64 d-rows x 256B
      int cI = seg * 256 + w * 64 + lane;
      int row = cI >> 4, sl = cI & 15;
      gl2lds16(Vh + (size_t)row * L_ + kk + ((sl ^ (row & 15)) * 8), (char*)vsb + cI * 16);
    }
    __syncthreads();

    #pragma unroll
    for (int p = 0; p < 4; ++p) {             // 4 groups of 32 keys
      short8 ka0[2], ka1[2];
      #pragma unroll
      for (int ks = 0; ks < 2; ++ks) {
        ka0[ks] = *(const short8*)((char*)ksb + (p * 32 + l16) * 128 + (((ks * 4 + quad) ^ (l16 & 7)) * 16));
        ka1[ks] = *(const short8*)((char*)ksb + (p * 32 + 16 + l16) * 128 + (((ks * 4 + quad) ^ (l16 & 7)) * 16));
      }
      short8 pt[4];
      #pragma unroll
      for (int qs = 0; qs < 4; ++qs) {
        floatx4 s0 = mfma16(ka0[0], qf[qs][0], fz);
        s0 = mfma16(ka0[1], qf[qs][1], s0);
        floatx4 s1 = mfma16(ka1[0], qf[qs][0], fz);
        s1 = mfma16(ka1[1], qf[qs][1], s1);
        float e0 = __builtin_amdgcn_exp2f(s0[0] * cexp);
        float e1 = __builtin_amdgcn_exp2f(s0[1] * cexp);
        float e2 = __builtin_amdgcn_exp2f(s0[2] * cexp);
        float e3 = __builtin_amdgcn_exp2f(s0[3] * cexp);
        float f0 = __builtin_amdgcn_exp2f(s1[0] * cexp);
        float f1 = __builtin_amdgcn_exp2f(s1[1] * cexp);
        float f2 = __builtin_amdgcn_exp2f(s1[2] * cexp);
        float f3 = __builtin_amdgcn_exp2f(s1[3] * cexp);
        union { uint4 u; short8 s; } pu;
        pu.u = make_uint4(pk2(e0, e1), pk2(e2, e3), pk2(f0, f1), pk2(f2, f3));
        pt[qs] = pu.s;
      }
      #pragma unroll
      for (int ds = 0; ds < 4; ++ds) {
        short8 va = *(const short8*)((char*)vsb + (ds * 16 + l16) * 256 + (((p * 4 + quad) ^ l16) * 16));
        #pragma unroll
        for (int qs = 0; qs < 4; ++qs)
          oT[ds][qs] = mfma16(va, pt[qs], oT[ds][qs]);
      }
    }
    __syncthreads();
  }

  // transpose O^T -> O via per-wave LDS region
  u16* ot = smem + w * 4608;   // 64 x 72 u16
  #pragma unroll
  for (int ds = 0; ds < 4; ++ds)
    #pragma unroll
    for (int qs = 0; qs < 4; ++qs)
      #pragma unroll
      for (int r = 0; r < 4; ++r)
        ot[(qs * 16 + l16) * 72 + ds * 16 + quad * 4 + r] = f2bf(oT[ds][qs][r]);
  __syncthreads();
  #pragma unroll
  for (int i = 0; i < 8; ++i) {
    int cc = i * 64 + lane;
    int ql = cc >> 3, d8 = cc & 7;
    short8 v = *(const short8*)(&ot[ql * 72 + d8 * 8]);
    *(short8*)(O + ((size_t)b * L_ + q0 + ql) * D_ + h * HD_ + d8 * 8) = v;
  }
}

extern "C" void kernel_launch(void* const* d_in, const int* in_sizes, int n_in,
                              void* d_out, int out_size, void* d_ws, size_t ws_size,
                              hipStream_t stream) {
  const float* xq = (const float*)d_in[0];
  const float* xk = (const float*)d_in[1];
  const float* xv = (const float*)d_in[2];
  const float* Wq = (const float*)d_in[4];
  const float* bq = (const float*)d_in[5];
  const float* Wk = (const float*)d_in[6];
  const float* bk = (const float*)d_in[7];
  const float* Wv = (const float*)d_in[8];
  const float* bv = (const float*)d_in[9];
  const float* Wo = (const float*)d_in[10];
  const float* bo = (const float*)d_in[11];

  char* ws = (char*)d_ws;
  const size_t MB = 1u << 20;
  dim3 blk(256);
  dim3 gg(8, 64);

  if (ws_size >= 90 * MB) {
    // fast path (89 MB high-water):
    //  [0,16)   xq_bf  -> Vt (after Q gemm)
    //  [16,32)  xk_bf  -> Ob (after K gemm)
    //  [32,48)  xv_bf
    //  [48,56)  WTq,WTk,WTv,WTo (2MB each)
    //  [56,57)  inv
    //  [57,73)  Q      [73,89) K
    u16* xqb = (u16*)(ws);
    u16* xkb = (u16*)(ws + 16 * MB);
    u16* xvb = (u16*)(ws + 32 * MB);
    u16* WTq = (u16*)(ws + 48 * MB);
    u16* WTk = (u16*)(ws + 50 * MB);
    u16* WTv = (u16*)(ws + 52 * MB);
    u16* WTo = (u16*)(ws + 54 * MB);
    float* invb = (float*)(ws + 56 * MB);
    u16* Qb = (u16*)(ws + 57 * MB);
    u16* Kb = (u16*)(ws + 73 * MB);
    u16* Vtb = (u16*)(ws);
    u16* Ob = (u16*)(ws + 16 * MB);

    cvtx3_k<<<dim3(4096, 3), blk, 0, stream>>>(xq, xk, xv, xqb, xkb, xvb);
    cvtw4_k<<<dim3(16, 16, 4), blk, 0, stream>>>(Wq, Wk, Wv, Wo, WTq, WTk, WTv, WTo);
    gemm2_k<1, 1><<<gg, blk, 0, stream>>>(xqb, WTq, bq, Qb, nullptr);
    gemm2_k<1, 1><<<gg, blk, 0, stream>>>(xkb, WTk, bk, Kb, nullptr);
    colsum2_k<<<dim3(4, 16, 8), blk, 0, stream>>>(Qb, Kb, invb);
    gemm2_k<1, 2><<<gg, blk, 0, stream>>>(xvb, WTv, bv, Vtb, invb);
    attn3_k<<<dim3(4, 16, 8), blk, 0, stream>>>(Qb, Kb, Vtb, Ob);
    gemm2_k<1, 0><<<gg, blk, 0, stream>>>(Ob, WTo, bo, (float*)d_out, nullptr);
  } else {
    // fallback: r3-proven 64 MB flow (V gemm reads fp32 xv directly)
    const size_t MB16 = 16u << 20;
    u16* Xbf  = (u16*)(ws);
    u16* Vtb  = (u16*)(ws);
    u16* Qb   = (u16*)(ws + MB16);
    u16* WT2  = (u16*)(ws + MB16);
    u16* Kb   = (u16*)(ws + 2 * MB16);
    u16* WT   = (u16*)(ws + 3 * MB16);
    float* invb = (float*)(ws + 3 * MB16 + (2u << 20));
    u16* Ob   = (u16*)(ws + 3 * MB16);

    cvtx3_k<<<dim3(4096, 1), blk, 0, stream>>>(xq, xq, xq, Xbf, Xbf, Xbf);
    cvtw4_k<<<dim3(16, 16, 1), blk, 0, stream>>>(Wq, Wq, Wq, Wq, WT, WT, WT, WT);
    gemm2_k<1, 1><<<gg, blk, 0, stream>>>(Xbf, WT, bq, Qb, nullptr);
    cvtx3_k<<<dim3(4096, 1), blk, 0, stream>>>(xk, xk, xk, Xbf, Xbf, Xbf);
    cvtw4_k<<<dim3(16, 16, 1), blk, 0, stream>>>(Wk, Wk, Wk, Wk, WT, WT, WT, WT);
    gemm2_k<1, 1><<<gg, blk, 0, stream>>>(Xbf, WT, bk, Kb, nullptr);
    colsum2_k<<<dim3(4, 16, 8), blk, 0, stream>>>(Qb, Kb, invb);
    cvtw4_k<<<dim3(16, 16, 1), blk, 0, stream>>>(Wv, Wv, Wv, Wv, WT, WT, WT, WT);
    gemm2_k<0, 2><<<gg, blk, 0, stream>>>(xv, WT, bv, Vtb, invb);
    attn3_k<<<dim3(4, 16, 8), blk, 0, stream>>>(Qb, Kb, Vtb, Ob);
    cvtw4_k<<<dim3(16, 16, 1), blk, 0, stream>>>(Wo, Wo, Wo, Wo, WT2, WT2, WT2, WT2);
    gemm2_k<1, 0><<<gg, blk, 0, stream>>>(Ob, WT2, bo, (float*)d_out, nullptr);
  }
}

// Round 5
// 314.871 us; speedup vs baseline: 2.1005x; 1.0668x over previous
//
#include <hip/hip_runtime.h>
#include <hip/hip_bf16.h>

// B=8, L=1024, D=1024, H=16, HD=64
#define B_ 8
#define L_ 1024
#define D_ 1024
#define H_ 16
#define HD_ 64

typedef short short8 __attribute__((ext_vector_type(8)));
typedef float floatx4 __attribute__((ext_vector_type(4)));
typedef unsigned short u16;

__device__ __forceinline__ u16 f2bf(float f) {          // RNE
  union { float f; unsigned u; } v; v.f = f;
  unsigned r = v.u + 0x7fffu + ((v.u >> 16) & 1u);
  return (u16)(r >> 16);
}
// pack bf16(a) low16, bf16(b) high16
__device__ __forceinline__ unsigned pk2(float a, float b) {
  union { float f; unsigned u; } x, y; x.f = a; y.f = b;
  return __builtin_amdgcn_perm(y.u + 0x8000u, x.u + 0x8000u, 0x07060302u);
}
__device__ __forceinline__ floatx4 mfma16(short8 a, short8 b, floatx4 c) {
  return __builtin_amdgcn_mfma_f32_16x16x32_bf16(a, b, c, 0, 0, 0);
}
__device__ __forceinline__ void gl2lds16(const void* g, void* l) {
  __builtin_amdgcn_global_load_lds(
      (const __attribute__((address_space(1))) void*)g,
      (__attribute__((address_space(3))) void*)l, 16, 0, 0);
}

#define KSCALE 0.04508422f   // log2(e)/32 folded into K projection

// ---- 3x: x fp32 [8M] -> bf16, grid (4096, nsel) ----
__global__ __launch_bounds__(256) void cvtx3_k(const float* __restrict__ x0,
    const float* __restrict__ x1, const float* __restrict__ x2,
    u16* __restrict__ y0, u16* __restrict__ y1, u16* __restrict__ y2) {
  const float* x = blockIdx.y == 0 ? x0 : (blockIdx.y == 1 ? x1 : x2);
  u16* y = blockIdx.y == 0 ? y0 : (blockIdx.y == 1 ? y1 : y2);
  size_t i = ((size_t)blockIdx.x * 256 + threadIdx.x) * 8;
  float4 a = *(const float4*)(x + i);
  float4 b = *(const float4*)(x + i + 4);
  uint4 u = make_uint4(pk2(a.x, a.y), pk2(a.z, a.w), pk2(b.x, b.y), pk2(b.z, b.w));
  *(uint4*)(y + i) = u;
}

// ---- 4x: W [K,N] fp32 -> Wt [N][K] bf16, grid (16,16,4) ----
__global__ __launch_bounds__(256) void cvtw4_k(
    const float* __restrict__ W0, const float* __restrict__ W1,
    const float* __restrict__ W2, const float* __restrict__ W3,
    u16* __restrict__ T0, u16* __restrict__ T1,
    u16* __restrict__ T2, u16* __restrict__ T3) {
  const int z = blockIdx.z;
  const float* W = z == 0 ? W0 : (z == 1 ? W1 : (z == 2 ? W2 : W3));
  u16* Wt = z == 0 ? T0 : (z == 1 ? T1 : (z == 2 ? T2 : T3));
  const int kt = blockIdx.x, nt = blockIdx.y;
  __shared__ __align__(16) u16 t[64 * 72];
  const int tid = threadIdx.x;
  #pragma unroll
  for (int i = 0; i < 4; ++i) {
    int idx = i * 256 + tid;
    int r = idx >> 4, c4 = idx & 15;
    float4 v = *(const float4*)(W + (size_t)(kt * 64 + r) * 1024 + nt * 64 + c4 * 4);
    t[(c4 * 4 + 0) * 72 + r] = f2bf(v.x);
    t[(c4 * 4 + 1) * 72 + r] = f2bf(v.y);
    t[(c4 * 4 + 2) * 72 + r] = f2bf(v.z);
    t[(c4 * 4 + 3) * 72 + r] = f2bf(v.w);
  }
  __syncthreads();
  #pragma unroll
  for (int i = 0; i < 2; ++i) {
    int idx = i * 256 + tid;
    int n = idx >> 3, k8 = idx & 7;
    short8 v = *(const short8*)(&t[n * 72 + k8 * 8]);
    *(short8*)(Wt + (size_t)(nt * 64 + n) * 1024 + kt * 64 + k8 * 8) = v;
  }
}

// ---- GEMM: C[8192,1024] = A @ Wt^T + bias ----  BK=64
// grid (64, 8): x=mt, y=nt -> A-slab sharers land on the same XCD (id%8)
// AMODE: 0 = A fp32, 1 = A bf16
// OUTM : 0 = fp32 [M,N]; 1 = bf16 head [B,H,L,HD], scaled by `scale`;
//        2 = bf16 V^T [B*D][L] scaled by inv[key], keys PERMUTED within
//            32-groups: pos = g*32 + quad*8 + kt*4 + r  <- key g*32+kt*16+quad*4+r
template<int AMODE, int OUTM>
__global__ __launch_bounds__(256, 2) void gemm2_k(const void* __restrict__ Ap,
    const u16* __restrict__ Bt, const float* __restrict__ bias,
    void* __restrict__ Cp, const float* __restrict__ inv, float scale)
{
  const int mt = blockIdx.x, nt = blockIdx.y;
  const int tid = threadIdx.x, lane = tid & 63, w = tid >> 6;
  const int quad = lane >> 4, l16 = lane & 15;
  const int wm = w >> 1, wn = w & 1;
  const int m0 = mt * 128, n0 = nt * 128;

  constexpr int ABYTES = AMODE ? 16384 : 32768;
  constexpr int STG = ABYTES + 16384;
  constexpr int SBYTES = (OUTM == 2 && STG < 34816) ? 34816 : STG;
  __shared__ __align__(16) char smem[SBYTES];
  char* AsB = smem;
  char* BsB = smem + ABYTES;

  const floatx4 fz = {0.f, 0.f, 0.f, 0.f};
  floatx4 acc[4][4];
  #pragma unroll
  for (int i = 0; i < 4; ++i)
    #pragma unroll
    for (int j = 0; j < 4; ++j) acc[i][j] = fz;

  for (int k0 = 0; k0 < 1024; k0 += 64) {
    #pragma unroll
    for (int seg = 0; seg < 4; ++seg) {
      int cI = seg * 256 + w * 64 + lane;
      int r = cI >> 3, sl = cI & 7;
      int kc = sl ^ (r & 7);
      gl2lds16(Bt + (size_t)(n0 + r) * 1024 + k0 + kc * 8, BsB + cI * 16);
    }
    if constexpr (AMODE == 0) {   // A fp32: 128 rows x 256B, 16 slots
      const float* A = (const float*)Ap;
      #pragma unroll
      for (int seg = 0; seg < 8; ++seg) {
        int cI = seg * 256 + w * 64 + lane;
        int r = cI >> 4, sl = cI & 15;
        int kc = sl ^ (r & 15);
        gl2lds16(A + (size_t)(m0 + r) * 1024 + k0 + kc * 4, AsB + cI * 16);
      }
    } else {                      // A bf16: 128 rows x 128B, 8 slots
      const u16* A = (const u16*)Ap;
      #pragma unroll
      for (int seg = 0; seg < 4; ++seg) {
        int cI = seg * 256 + w * 64 + lane;
        int r = cI >> 3, sl = cI & 7;
        int kc = sl ^ (r & 7);
        gl2lds16(A + (size_t)(m0 + r) * 1024 + k0 + kc * 8, AsB + cI * 16);
      }
    }
    __syncthreads();

    #pragma unroll
    for (int ks = 0; ks < 2; ++ks) {
      short8 af[4], bfv[4];
      #pragma unroll
      for (int mf = 0; mf < 4; ++mf) {
        int row = wm * 64 + mf * 16 + l16;
        if constexpr (AMODE == 0) {
          int L0 = ks * 8 + quad * 2;
          float4 x0 = *(const float4*)(AsB + row * 256 + ((L0) ^ l16) * 16);
          float4 x1 = *(const float4*)(AsB + row * 256 + ((L0 + 1) ^ l16) * 16);
          union { uint4 u; short8 s; } uu;
          uu.u = make_uint4(pk2(x0.x, x0.y), pk2(x0.z, x0.w),
                            pk2(x1.x, x1.y), pk2(x1.z, x1.w));
          af[mf] = uu.s;
        } else {
          af[mf] = *(const short8*)(AsB + row * 128 + (((ks * 4 + quad) ^ (l16 & 7)) * 16));
        }
      }
      #pragma unroll
      for (int nf = 0; nf < 4; ++nf) {
        int row = wn * 64 + nf * 16 + l16;
        bfv[nf] = *(const short8*)(BsB + row * 128 + (((ks * 4 + quad) ^ (l16 & 7)) * 16));
      }
      #pragma unroll
      for (int mf = 0; mf < 4; ++mf)
        #pragma unroll
        for (int nf = 0; nf < 4; ++nf)
          acc[mf][nf] = mfma16(af[mf], bfv[nf], acc[mf][nf]);
    }
    __syncthreads();
  }

  float bv[4];
  #pragma unroll
  for (int nf = 0; nf < 4; ++nf) bv[nf] = bias[n0 + wn * 64 + nf * 16 + l16];

  if constexpr (OUTM == 0) {
    float* C = (float*)Cp;
    #pragma unroll
    for (int mf = 0; mf < 4; ++mf)
      #pragma unroll
      for (int nf = 0; nf < 4; ++nf) {
        int n = n0 + wn * 64 + nf * 16 + l16;
        #pragma unroll
        for (int r = 0; r < 4; ++r) {
          int m = m0 + wm * 64 + mf * 16 + quad * 4 + r;
          C[(size_t)m * 1024 + n] = acc[mf][nf][r] + bv[nf];
        }
      }
  } else if constexpr (OUTM == 1) {
    u16* C = (u16*)Cp;
    #pragma unroll
    for (int mf = 0; mf < 4; ++mf)
      #pragma unroll
      for (int nf = 0; nf < 4; ++nf) {
        int n = n0 + wn * 64 + nf * 16 + l16;
        #pragma unroll
        for (int r = 0; r < 4; ++r) {
          int m = m0 + wm * 64 + mf * 16 + quad * 4 + r;
          int bb = m >> 10, l = m & 1023, hh = n >> 6, hd = n & 63;
          C[((size_t)((bb * H_ + hh) * L_) + l) * HD_ + hd] =
              f2bf((acc[mf][nf][r] + bv[nf]) * scale);
        }
      }
  } else {  // OUTM == 2: scaled V^T, permuted key order
    u16* ct = (u16*)smem;            // 128 x 136 u16
    const int bb = m0 >> 10;
    const int hrow = bb * 16 + (n0 >> 6) + wn;
    float ivv[4][4];
    #pragma unroll
    for (int mf = 0; mf < 4; ++mf)
      #pragma unroll
      for (int r = 0; r < 4; ++r)
        ivv[mf][r] = inv[(size_t)hrow * 1024 + (m0 & 1023) + wm * 64 + mf * 16 + quad * 4 + r];
    __syncthreads();
    #pragma unroll
    for (int mf = 0; mf < 4; ++mf)
      #pragma unroll
      for (int nf = 0; nf < 4; ++nf)
        #pragma unroll
        for (int r = 0; r < 4; ++r) {
          float val = (acc[mf][nf][r] + bv[nf]) * ivv[mf][r];
          ct[(wn * 64 + nf * 16 + l16) * 136 + wm * 64 + mf * 16 + quad * 4 + r] = f2bf(val);
        }
    __syncthreads();
    u16* Vt = (u16*)Cp;
    #pragma unroll
    for (int i = 0; i < 8; ++i) {
      int cc = i * 256 + tid;
      int n = cc >> 4, l8 = cc & 15;
      int g = l8 >> 2, q2 = l8 & 3;
      int mloc = g * 32 + q2 * 4;
      uint2 lo = *(const uint2*)(&ct[n * 136 + mloc]);
      uint2 hi = *(const uint2*)(&ct[n * 136 + mloc + 16]);
      uint4 uv = make_uint4(lo.x, lo.y, hi.x, hi.y);
      *(uint4*)(Vt + ((size_t)bb * 1024 + n0 + n) * 1024 + (m0 & 1023) + l8 * 8) = uv;
    }
  }
}

// ---- colsum: inv[b,h,k] = 1/sum_q exp2(S'[q,k]); K pre-scaled by log2e/32 ----
// grid (128, 4): x = head (same-head blocks share an XCD), y = ktb
__global__ __launch_bounds__(256, 2) void colsum2_k(const u16* __restrict__ Q,
    const u16* __restrict__ K, float* __restrict__ inv)
{
  const int hh = blockIdx.x, ktb = blockIdx.y;
  const int tid = threadIdx.x, lane = tid & 63, w = tid >> 6;
  const int quad = lane >> 4, l16 = lane & 15;
  const size_t hb = (size_t)hh * L_ * HD_;
  const u16* Qh = Q + hb;
  const u16* Kh = K + hb;
  const int kbase = ktb * 256 + w * 64;
  const floatx4 fz = {0.f, 0.f, 0.f, 0.f};

  __shared__ __align__(16) u16 qsm[16384];   // 256 q-rows x 64 bf16, swizzled

  short8 kf[4][2];
  #pragma unroll
  for (int nf = 0; nf < 4; ++nf)
    #pragma unroll
    for (int ks = 0; ks < 2; ++ks)
      kf[nf][ks] = *(const short8*)(Kh + (size_t)(kbase + nf * 16 + l16) * 64 + ks * 32 + quad * 8);

  float cs[4] = {0.f, 0.f, 0.f, 0.f};
  for (int qc = 0; qc < 4; ++qc) {
    #pragma unroll
    for (int seg = 0; seg < 8; ++seg) {
      int cI = seg * 256 + w * 64 + lane;
      int row = cI >> 3, sl = cI & 7;
      gl2lds16(Qh + (size_t)(qc * 256 + row) * 64 + ((sl ^ (row & 7)) * 8), (char*)qsm + cI * 16);
    }
    __syncthreads();
    #pragma unroll
    for (int mf = 0; mf < 16; ++mf) {
      short8 qf0 = *(const short8*)(&qsm[(mf * 16 + l16) * 64 + ((quad ^ (l16 & 7)) * 8)]);
      short8 qf1 = *(const short8*)(&qsm[(mf * 16 + l16) * 64 + (((4 + quad) ^ (l16 & 7)) * 8)]);
      floatx4 sacc[4];
      #pragma unroll
      for (int nf = 0; nf < 4; ++nf) {
        floatx4 s = mfma16(qf0, kf[nf][0], fz);
        sacc[nf] = mfma16(qf1, kf[nf][1], s);
      }
      #pragma unroll
      for (int nf = 0; nf < 4; ++nf)
        #pragma unroll
        for (int r = 0; r < 4; ++r)
          cs[nf] += __builtin_amdgcn_exp2f(sacc[nf][r]);
    }
    __syncthreads();
  }
  #pragma unroll
  for (int nf = 0; nf < 4; ++nf) {
    cs[nf] += __shfl_xor(cs[nf], 16);
    cs[nf] += __shfl_xor(cs[nf], 32);
  }
  if (quad == 0) {
    #pragma unroll
    for (int nf = 0; nf < 4; ++nf)
      inv[(size_t)hh * L_ + kbase + nf * 16 + l16] = 1.0f / cs[nf];
  }
}

// ---- attention: LDS double-buffered K + permuted V^T, 128-key chunks ----
// grid (128, 4): x = head, y = qb. K pre-scaled so P = exp2(S') directly.
__global__ __launch_bounds__(256, 2) void attn3_k(const u16* __restrict__ Q,
    const u16* __restrict__ K, const u16* __restrict__ Vt, u16* __restrict__ O)
{
  const int hh = blockIdx.x, qb = blockIdx.y;
  const int b = hh >> 4, h = hh & 15;
  const int tid = threadIdx.x, lane = tid & 63, w = tid >> 6;
  const int quad = lane >> 4, l16 = lane & 15;
  const size_t hb = (size_t)hh * L_ * HD_;
  const u16* Qh = Q + hb;
  const u16* Kh = K + hb;
  const u16* Vh = Vt + ((size_t)b * D_ + h * HD_) * L_;   // [d][pos], stride L
  const int q0 = qb * 256 + w * 64;
  const floatx4 fz = {0.f, 0.f, 0.f, 0.f};

  // double buffer: buf b at byte offset b*32768; K 16KB + V 16KB each.
  // epilogue transpose (36864B) reuses the same 64KB.
  __shared__ __align__(16) u16 smem[32768];

  short8 qf[4][2];            // B-operand frags of Q
  #pragma unroll
  for (int qs = 0; qs < 4; ++qs)
    #pragma unroll
    for (int ks = 0; ks < 2; ++ks)
      qf[qs][ks] = *(const short8*)(Qh + (size_t)(q0 + qs * 16 + l16) * 64 + ks * 32 + quad * 8);

  floatx4 oT[4][4];           // O^T: row d=ds*16+quad*4+r, col q=qs*16+l16
  #pragma unroll
  for (int i = 0; i < 4; ++i)
    #pragma unroll
    for (int j = 0; j < 4; ++j) oT[i][j] = fz;

  // stage chunk kc into buffer buf
  auto stage = [&](int kc, int buf) {
    const int kk = kc * 128;
    char* kdst = (char*)smem + buf * 32768;
    char* vdst = kdst + 16384;
    #pragma unroll
    for (int seg = 0; seg < 4; ++seg) {       // K: 128 rows x 128B
      int cI = seg * 256 + w * 64 + lane;
      int row = cI >> 3, sl = cI & 7;
      gl2lds16(Kh + (size_t)(kk + row) * 64 + ((sl ^ (row & 7)) * 8), kdst + cI * 16);
    }
    #pragma unroll
    for (int seg = 0; seg < 4; ++seg) {       // V: 64 d-rows x 256B
      int cI = seg * 256 + w * 64 + lane;
      int row = cI >> 4, sl = cI & 15;
      gl2lds16(Vh + (size_t)row * L_ + kk + ((sl ^ (row & 15)) * 8), vdst + cI * 16);
    }
  };

  stage(0, 0);
  __syncthreads();
  int buf = 0;
  for (int kc = 0; kc < 8; ++kc) {
    if (kc < 7) stage(kc + 1, buf ^ 1);
    char* ksb = (char*)smem + buf * 32768;
    char* vsb = ksb + 16384;

    #pragma unroll
    for (int p = 0; p < 4; ++p) {             // 4 groups of 32 keys
      short8 ka0[2], ka1[2];
      #pragma unroll
      for (int ks = 0; ks < 2; ++ks) {
        ka0[ks] = *(const short8*)(ksb + (p * 32 + l16) * 128 + (((ks * 4 + quad) ^ (l16 & 7)) * 16));
        ka1[ks] = *(const short8*)(ksb + (p * 32 + 16 + l16) * 128 + (((ks * 4 + quad) ^ (l16 & 7)) * 16));
      }
      short8 pt[4];
      #pragma unroll
      for (int qs = 0; qs < 4; ++qs) {
        floatx4 s0 = mfma16(ka0[0], qf[qs][0], fz);
        s0 = mfma16(ka0[1], qf[qs][1], s0);
        floatx4 s1 = mfma16(ka1[0], qf[qs][0], fz);
        s1 = mfma16(ka1[1], qf[qs][1], s1);
        float e0 = __builtin_amdgcn_exp2f(s0[0]);
        float e1 = __builtin_amdgcn_exp2f(s0[1]);
        float e2 = __builtin_amdgcn_exp2f(s0[2]);
        float e3 = __builtin_amdgcn_exp2f(s0[3]);
        float f0 = __builtin_amdgcn_exp2f(s1[0]);
        float f1 = __builtin_amdgcn_exp2f(s1[1]);
        float f2 = __builtin_amdgcn_exp2f(s1[2]);
        float f3 = __builtin_amdgcn_exp2f(s1[3]);
        union { uint4 u; short8 s; } pu;
        pu.u = make_uint4(pk2(e0, e1), pk2(e2, e3), pk2(f0, f1), pk2(f2, f3));
        pt[qs] = pu.s;
      }
      #pragma unroll
      for (int ds = 0; ds < 4; ++ds) {
        short8 va = *(const short8*)(vsb + (ds * 16 + l16) * 256 + (((p * 4 + quad) ^ l16) * 16));
        #pragma unroll
        for (int qs = 0; qs < 4; ++qs)
          oT[ds][qs] = mfma16(va, pt[qs], oT[ds][qs]);
      }
    }
    __syncthreads();
    buf ^= 1;
  }

  // transpose O^T -> O via per-wave LDS region
  u16* ot = smem + w * 4608;   // 64 x 72 u16
  #pragma unroll
  for (int ds = 0; ds < 4; ++ds)
    #pragma unroll
    for (int qs = 0; qs < 4; ++qs)
      #pragma unroll
      for (int r = 0; r < 4; ++r)
        ot[(qs * 16 + l16) * 72 + ds * 16 + quad * 4 + r] = f2bf(oT[ds][qs][r]);
  __syncthreads();
  #pragma unroll
  for (int i = 0; i < 8; ++i) {
    int cc = i * 64 + lane;
    int ql = cc >> 3, d8 = cc & 7;
    short8 v = *(const short8*)(&ot[ql * 72 + d8 * 8]);
    *(short8*)(O + ((size_t)b * L_ + q0 + ql) * D_ + h * HD_ + d8 * 8) = v;
  }
}

extern "C" void kernel_launch(void* const* d_in, const int* in_sizes, int n_in,
                              void* d_out, int out_size, void* d_ws, size_t ws_size,
                              hipStream_t stream) {
  const float* xq = (const float*)d_in[0];
  const float* xk = (const float*)d_in[1];
  const float* xv = (const float*)d_in[2];
  const float* Wq = (const float*)d_in[4];
  const float* bq = (const float*)d_in[5];
  const float* Wk = (const float*)d_in[6];
  const float* bk = (const float*)d_in[7];
  const float* Wv = (const float*)d_in[8];
  const float* bv = (const float*)d_in[9];
  const float* Wo = (const float*)d_in[10];
  const float* bo = (const float*)d_in[11];

  char* ws = (char*)d_ws;
  const size_t MB = 1u << 20;
  dim3 blk(256);
  dim3 gg(64, 8);             // x=mt, y=nt: A-sharers on same XCD

  if (ws_size >= 90 * MB) {
    // fast path (89 MB high-water):
    //  [0,16)   xq_bf  -> Vt (after Q gemm)
    //  [16,32)  xk_bf  -> Ob (after K gemm)
    //  [32,48)  xv_bf
    //  [48,56)  WTq,WTk,WTv,WTo (2MB each)
    //  [56,57)  inv
    //  [57,73)  Q      [73,89) K
    u16* xqb = (u16*)(ws);
    u16* xkb = (u16*)(ws + 16 * MB);
    u16* xvb = (u16*)(ws + 32 * MB);
    u16* WTq = (u16*)(ws + 48 * MB);
    u16* WTk = (u16*)(ws + 50 * MB);
    u16* WTv = (u16*)(ws + 52 * MB);
    u16* WTo = (u16*)(ws + 54 * MB);
    float* invb = (float*)(ws + 56 * MB);
    u16* Qb = (u16*)(ws + 57 * MB);
    u16* Kb = (u16*)(ws + 73 * MB);
    u16* Vtb = (u16*)(ws);
    u16* Ob = (u16*)(ws + 16 * MB);

    cvtx3_k<<<dim3(4096, 3), blk, 0, stream>>>(xq, xk, xv, xqb, xkb, xvb);
    cvtw4_k<<<dim3(16, 16, 4), blk, 0, stream>>>(Wq, Wk, Wv, Wo, WTq, WTk, WTv, WTo);
    gemm2_k<1, 1><<<gg, blk, 0, stream>>>(xqb, WTq, bq, Qb, nullptr, 1.0f);
    gemm2_k<1, 1><<<gg, blk, 0, stream>>>(xkb, WTk, bk, Kb, nullptr, KSCALE);
    colsum2_k<<<dim3(128, 4), blk, 0, stream>>>(Qb, Kb, invb);
    gemm2_k<1, 2><<<gg, blk, 0, stream>>>(xvb, WTv, bv, Vtb, invb, 1.0f);
    attn3_k<<<dim3(128, 4), blk, 0, stream>>>(Qb, Kb, Vtb, Ob);
    gemm2_k<1, 0><<<gg, blk, 0, stream>>>(Ob, WTo, bo, (float*)d_out, nullptr, 1.0f);
  } else {
    // fallback: 64 MB flow (V gemm reads fp32 xv directly)
    const size_t MB16 = 16u << 20;
    u16* Xbf  = (u16*)(ws);
    u16* Vtb  = (u16*)(ws);
    u16* Qb   = (u16*)(ws + MB16);
    u16* WT2  = (u16*)(ws + MB16);
    u16* Kb   = (u16*)(ws + 2 * MB16);
    u16* WT   = (u16*)(ws + 3 * MB16);
    float* invb = (float*)(ws + 3 * MB16 + (2u << 20));
    u16* Ob   = (u16*)(ws + 3 * MB16);

    cvtx3_k<<<dim3(4096, 1), blk, 0, stream>>>(xq, xq, xq, Xbf, Xbf, Xbf);
    cvtw4_k<<<dim3(16, 16, 1), blk, 0, stream>>>(Wq, Wq, Wq, Wq, WT, WT, WT, WT);
    gemm2_k<1, 1><<<gg, blk, 0, stream>>>(Xbf, WT, bq, Qb, nullptr, 1.0f);
    cvtx3_k<<<dim3(4096, 1), blk, 0, stream>>>(xk, xk, xk, Xbf, Xbf, Xbf);
    cvtw4_k<<<dim3(16, 16, 1), blk, 0, stream>>>(Wk, Wk, Wk, Wk, WT, WT, WT, WT);
    gemm2_k<1, 1><<<gg, blk, 0, stream>>>(Xbf, WT, bk, Kb, nullptr, KSCALE);
    colsum2_k<<<dim3(128, 4), blk, 0, stream>>>(Qb, Kb, invb);
    cvtw4_k<<<dim3(16, 16, 1), blk, 0, stream>>>(Wv, Wv, Wv, Wv, WT, WT, WT, WT);
    gemm2_k<0, 2><<<gg, blk, 0, stream>>>(xv, WT, bv, Vtb, invb, 1.0f);
    attn3_k<<<dim3(128, 4), blk, 0, stream>>>(Qb, Kb, Vtb, Ob);
    cvtw4_k<<<dim3(16, 16, 1), blk, 0, stream>>>(Wo, Wo, Wo, Wo, WT2, WT2, WT2, WT2);
    gemm2_k<1, 0><<<gg, blk, 0, stream>>>(Ob, WT2, bo, (float*)d_out, nullptr, 1.0f);
  }
}